// Round 1
// 799.052 us; speedup vs baseline: 1.0015x; 1.0015x over previous
//
#include <hip/hip_runtime.h>
#include <hip/hip_bf16.h>
#include <math.h>

#define DI __device__ __forceinline__

typedef __bf16 bf16x8 __attribute__((ext_vector_type(8)));
typedef float f32x4 __attribute__((ext_vector_type(4)));
typedef short s16x8 __attribute__((ext_vector_type(8)));

// ---------- helpers ----------
DI unsigned short f2bf(float f) {
  unsigned int u = __builtin_bit_cast(unsigned int, f);
  unsigned int r = (u + 0x7fffu + ((u >> 16) & 1u)) >> 16;
  return (unsigned short)r;
}
DI float bf2f(unsigned short h) {
  unsigned int u = ((unsigned int)h) << 16;
  return __builtin_bit_cast(float, u);
}

DI void gload16(const void* g, void* l) {
  __builtin_amdgcn_global_load_lds(
      (const __attribute__((address_space(1))) void*)g,
      (__attribute__((address_space(3))) void*)l, 16, 0, 0);
}

// 2-D XCD rasterization: XCD grid 2(m) x 4(n); within an XCD, m-fastest so the
// ~32 co-resident blocks form an 8m x 4n rectangle (L2 panel reuse). ny == 16.
DI void xcd_map(int BN, int& m0, int& n0) {
  const int nx = gridDim.x;
  int orig = blockIdx.y * nx + blockIdx.x;
  int xcd = orig & 7, k = orig >> 3;
  int xm = xcd >> 2, xn = xcd & 3;
  int nband = nx >> 2;
  m0 = (xm * 8 + (k & 7)) * 256;
  n0 = (xn * nband + (k >> 3)) * BN;
}

// ---------- transpose + fp32->bf16 cast: out[c][r] = bf16(in[r][c]) ----------
__global__ __launch_bounds__(256)
void transpose_cast_f32(const float* __restrict__ in, unsigned short* __restrict__ out,
                        int R, int C) {
  __shared__ unsigned int t[64 * 65];
  const int r0 = blockIdx.y * 64, c0 = blockIdx.x * 64;
  const int tid = threadIdx.x;
#pragma unroll
  for (int p = 0; p < 4; ++p) {
    int e = p * 1024 + tid * 4;
    int r = e >> 6, c = e & 63;
    float4 v = *(const float4*)(in + (size_t)(r0 + r) * C + c0 + c);
    t[r * 65 + c + 0] = f2bf(v.x);
    t[r * 65 + c + 1] = f2bf(v.y);
    t[r * 65 + c + 2] = f2bf(v.z);
    t[r * 65 + c + 3] = f2bf(v.w);
  }
  __syncthreads();
  const int oc = tid >> 2, ch = tid & 3;
  alignas(16) unsigned short vals[16];
#pragma unroll
  for (int j = 0; j < 16; ++j) vals[j] = (unsigned short)t[(ch * 16 + j) * 65 + oc];
  size_t ob = (size_t)(c0 + oc) * R + r0 + ch * 16;
  *(s16x8*)(out + ob) = *(const s16x8*)(vals);
  *(s16x8*)(out + ob + 8) = *(const s16x8*)(vals + 8);
}

// ---------- V transpose: qkv[b][s][4096+h*128+d] -> vT[bh][d][s] (bf16) ----------
__global__ __launch_bounds__(256)
void transpose_v(const unsigned short* __restrict__ qkv, unsigned short* __restrict__ vT) {
  __shared__ unsigned int t[64 * 65];
  const int s0 = blockIdx.x * 64, d0 = blockIdx.y * 64, bh = blockIdx.z;
  const int b = bh >> 4, h = bh & 15;
  const int tid = threadIdx.x;
#pragma unroll
  for (int p = 0; p < 2; ++p) {
    int id = p * 256 + tid;
    int r = id >> 3, c = (id & 7) * 8;
    s16x8 v = *(const s16x8*)(qkv + (size_t)(b * 2048 + s0 + r) * 6144 + 4096 + h * 128 + d0 + c);
#pragma unroll
    for (int j = 0; j < 8; ++j) t[r * 65 + c + j] = (unsigned short)((const unsigned short*)&v)[j];
  }
  __syncthreads();
  const int oc = tid >> 2, ch = tid & 3;
  alignas(16) unsigned short vals[16];
#pragma unroll
  for (int j = 0; j < 16; ++j) vals[j] = (unsigned short)t[(ch * 16 + j) * 65 + oc];
  size_t ob = (size_t)(bh * 128 + d0 + oc) * 2048 + s0 + ch * 16;
  *(s16x8*)(vT + ob) = *(const s16x8*)(vals);
  *(s16x8*)(vT + ob + 8) = *(const s16x8*)(vals + 8);
}

// ---------- LayerNorm fp32 -> bf16, row = 2048 ----------
__global__ __launch_bounds__(256)
void ln_kernel(const float* __restrict__ x, const float* __restrict__ g,
               const float* __restrict__ bi, unsigned short* __restrict__ y) {
  __shared__ float red[8];
  const int row = blockIdx.x, tid = threadIdx.x;
  const float* xp = x + (size_t)row * 2048 + tid * 8;
  float4 v0 = *(const float4*)xp;
  float4 v1 = *(const float4*)(xp + 4);
  float v[8] = {v0.x, v0.y, v0.z, v0.w, v1.x, v1.y, v1.z, v1.w};
  float s = 0.f;
#pragma unroll
  for (int j = 0; j < 8; ++j) s += v[j];
#pragma unroll
  for (int d = 1; d < 64; d <<= 1) s += __shfl_xor(s, d);
  if ((tid & 63) == 0) red[tid >> 6] = s;
  __syncthreads();
  float mean = (red[0] + red[1] + red[2] + red[3]) * (1.f / 2048.f);
  float dd[8], sq = 0.f;
#pragma unroll
  for (int j = 0; j < 8; ++j) { dd[j] = v[j] - mean; sq += dd[j] * dd[j]; }
#pragma unroll
  for (int d = 1; d < 64; d <<= 1) sq += __shfl_xor(sq, d);
  if ((tid & 63) == 0) red[4 + (tid >> 6)] = sq;
  __syncthreads();
  float var = (red[4] + red[5] + red[6] + red[7]) * (1.f / 2048.f);
  float rs = rsqrtf(var + 1e-5f);
  float4 g0 = *(const float4*)(g + tid * 8), g1 = *(const float4*)(g + tid * 8 + 4);
  float4 b0 = *(const float4*)(bi + tid * 8), b1 = *(const float4*)(bi + tid * 8 + 4);
  float gg[8] = {g0.x, g0.y, g0.z, g0.w, g1.x, g1.y, g1.z, g1.w};
  float bb[8] = {b0.x, b0.y, b0.z, b0.w, b1.x, b1.y, b1.z, b1.w};
  alignas(16) unsigned short o[8];
#pragma unroll
  for (int j = 0; j < 8; ++j) o[j] = f2bf(dd[j] * rs * gg[j] + bb[j]);
  *(s16x8*)(y + (size_t)row * 2048 + tid * 8) = *(const s16x8*)o;
}

// ---------- shared GEMM staging helpers ----------
DI void stage_half(const unsigned short* __restrict__ G, int ld, int rbase, int kt,
                   int h, unsigned short* dst, int tid) {
#pragma unroll
  for (int i = 0; i < 2; ++i) {
    int id = i * 512 + tid;
    int rl = id >> 3, sl = id & 7;
    int ss = sl ^ (rl & 7);
    gload16(G + (size_t)(rbase + h * 128 + rl) * ld + kt + ss * 8,
            (char*)dst + h * 16384 + id * 16);
  }
}

DI bf16x8 ldsrd(const unsigned short* buf, int row, int ks) {
  return *(const bf16x8*)((const char*)buf + row * 128 + ((ks ^ (row & 7)) << 4));
}

// ---------- 256x256 GEMM, 4 clusters/K-tile, read-hoisted schedule ----------
// Reads for cluster C are issued under cluster C-1 so LDS drain overlaps MFMA.
// Barriers: one per cluster (4/iter, was 8). Stage placement, counted vmcnt(6)
// pipeline, and buffer alternation are IDENTICAL to the verified 8-barrier
// version; every stage X(t+2)->cur sits after [per-wave compiler lgkm drain of
// X's readers' cluster] -> [that cluster's end barrier], so cross-wave safety
// is unchanged.
// MODE 0: out bf16 = acc + bias ; MODE 1: out f32 = acc + bias + res
template <int MODE>
__global__ __launch_bounds__(512, 2)
void gemm256(const unsigned short* __restrict__ A, int lda,
             const unsigned short* __restrict__ B,
             const float* __restrict__ bias,
             const void* __restrict__ resg,
             void* __restrict__ out, int ldc, int K) {
  __shared__ alignas(16) unsigned short As[2][256 * 64];
  __shared__ alignas(16) unsigned short Bs[2][256 * 64];

  const int tid = threadIdx.x;
  const int l = tid & 63, w = tid >> 6;
  const int wr = w >> 2, wc = w & 3;
  const int lr = l & 15, lg = l >> 4;

  int m0, n0;
  xcd_map(256, m0, n0);

  const int NT = K >> 6;

  f32x4 acc[8][4];
  const f32x4 z4 = {0.f, 0.f, 0.f, 0.f};
#pragma unroll
  for (int i = 0; i < 8; ++i)
#pragma unroll
    for (int j = 0; j < 4; ++j) acc[i][j] = z4;

  stage_half(A, lda, m0, 0, 0, As[0], tid);
  stage_half(A, lda, m0, 0, 1, As[0], tid);
  stage_half(B, K, n0, 0, 0, Bs[0], tid);
  stage_half(B, K, n0, 0, 1, Bs[0], tid);
  if (NT > 1) {
    stage_half(B, K, n0, 64, 0, Bs[1], tid);
    stage_half(B, K, n0, 64, 1, Bs[1], tid);
    stage_half(A, lda, m0, 64, 0, As[1], tid);
    asm volatile("s_waitcnt vmcnt(6)" ::: "memory");
  } else {
    asm volatile("s_waitcnt vmcnt(0)" ::: "memory");
  }
  __builtin_amdgcn_s_barrier();

  for (int t = 0; t < NT; ++t) {
    const int cur = t & 1;
    const unsigned short* Ac = As[cur];
    const unsigned short* Bc = Bs[cur];
    bf16x8 a0[4][2], a1[4][2], bfr[4][2];

    // ---- c1: issue a0(8)+b0123(8); stage A-h1(t+1)->nxt; Q1 = a0 x b01 ----
    // (b23 drains under Q1; compiler waits only on a0/b01 before the MFMAs)
#pragma unroll
    for (int i = 0; i < 4; ++i)
#pragma unroll
      for (int kk = 0; kk < 2; ++kk)
        a0[i][kk] = ldsrd(Ac, wr * 128 + i * 16 + lr, kk * 4 + lg);
#pragma unroll
    for (int j = 0; j < 2; ++j)
#pragma unroll
      for (int kk = 0; kk < 2; ++kk)
        bfr[j][kk] = ldsrd(Bc, wc * 64 + j * 16 + lr, kk * 4 + lg);
    if (t + 1 < NT) stage_half(A, lda, m0, (t + 1) * 64, 1, As[cur ^ 1], tid);
#pragma unroll
    for (int j = 2; j < 4; ++j)
#pragma unroll
      for (int kk = 0; kk < 2; ++kk)
        bfr[j][kk] = ldsrd(Bc, wc * 64 + j * 16 + lr, kk * 4 + lg);
    __builtin_amdgcn_s_setprio(1);
#pragma unroll
    for (int i = 0; i < 4; ++i)
#pragma unroll
      for (int j = 0; j < 2; ++j)
#pragma unroll
        for (int kk = 0; kk < 2; ++kk)
          acc[i][j] = __builtin_amdgcn_mfma_f32_16x16x32_bf16(a0[i][kk], bfr[j][kk], acc[i][j], 0, 0, 0);
    __builtin_amdgcn_s_setprio(0);
    __builtin_amdgcn_s_barrier();

    // ---- c2: Q2 = a0 x b23; a1[i] issued as a0[i] dies (reg-neutral hoist) ----
    __builtin_amdgcn_s_setprio(1);
#pragma unroll
    for (int i = 0; i < 4; ++i) {
#pragma unroll
      for (int j = 2; j < 4; ++j)
#pragma unroll
        for (int kk = 0; kk < 2; ++kk)
          acc[i][j] = __builtin_amdgcn_mfma_f32_16x16x32_bf16(a0[i][kk], bfr[j][kk], acc[i][j], 0, 0, 0);
#pragma unroll
      for (int kk = 0; kk < 2; ++kk)
        a1[i][kk] = ldsrd(Ac, wr * 128 + 64 + i * 16 + lr, kk * 4 + lg);
    }
    __builtin_amdgcn_s_setprio(0);
    __builtin_amdgcn_s_barrier();

    // ---- c3: stage B-h0(t+2)->cur (all b reads drained pre-Q2 + barrier); Q3 ----
    if (t + 2 < NT) stage_half(B, K, n0, (t + 2) * 64, 0, Bs[cur], tid);
    __builtin_amdgcn_s_setprio(1);
#pragma unroll
    for (int i = 0; i < 4; ++i)
#pragma unroll
      for (int j = 0; j < 2; ++j)
#pragma unroll
        for (int kk = 0; kk < 2; ++kk)
          acc[i + 4][j] = __builtin_amdgcn_mfma_f32_16x16x32_bf16(a1[i][kk], bfr[j][kk], acc[i + 4][j], 0, 0, 0);
    __builtin_amdgcn_s_setprio(0);
    __builtin_amdgcn_s_barrier();

    // ---- c4: stage B-h1(t+2)+A-h0(t+2)->cur (a1 drained pre-Q3 + barrier); Q4 ----
    if (t + 2 < NT) {
      stage_half(B, K, n0, (t + 2) * 64, 1, Bs[cur], tid);
      stage_half(A, lda, m0, (t + 2) * 64, 0, As[cur], tid);
    }
    __builtin_amdgcn_s_setprio(1);
#pragma unroll
    for (int i = 0; i < 4; ++i)
#pragma unroll
      for (int j = 2; j < 4; ++j)
#pragma unroll
        for (int kk = 0; kk < 2; ++kk)
          acc[i + 4][j] = __builtin_amdgcn_mfma_f32_16x16x32_bf16(a1[i][kk], bfr[j][kk], acc[i + 4][j], 0, 0, 0);
    __builtin_amdgcn_s_setprio(0);
    if (t + 2 < NT) {
      asm volatile("s_waitcnt vmcnt(6)" ::: "memory");
    } else {
      asm volatile("s_waitcnt vmcnt(0)" ::: "memory");
    }
    __builtin_amdgcn_s_barrier();
  }

#pragma unroll
  for (int i = 0; i < 8; ++i) {
    int r0 = m0 + wr * 128 + i * 16 + lg * 4;
#pragma unroll
    for (int j = 0; j < 4; ++j) {
      int col = n0 + wc * 64 + j * 16 + lr;
      float bb = bias[col];
#pragma unroll
      for (int q = 0; q < 4; ++q) {
        size_t off = (size_t)(r0 + q) * ldc + col;
        float v = acc[i][j][q] + bb;
        if (MODE == 0) {
          ((unsigned short*)out)[off] = f2bf(v);
        } else {
          ((float*)out)[off] = v + ((const float*)resg)[off];
        }
      }
    }
  }
}

// ---------- 256x128 GEMM, single-B (2-cluster) or dual-B (4-cluster, silu fuse) --
// Same read-hoisted schedule as gemm256: reads for cluster C issue under C-1,
// one barrier per cluster, stage placement + counted vmcnt identical to the
// verified version.
// MODE 1: out f32 = acc0 + bias0 + res ; MODE 2 (DUAL): out bf16 = (acc0+bias0)*silu(acc1+bias1)
template <int MODE, bool DUAL>
__global__ __launch_bounds__(512, 2)
void gemm_n128(const unsigned short* __restrict__ A, int lda,
               const unsigned short* __restrict__ B0,
               const unsigned short* __restrict__ B1,
               const float* __restrict__ bias0, const float* __restrict__ bias1,
               const void* __restrict__ resg,
               void* __restrict__ out, int ldc, int K) {
  __shared__ alignas(16) unsigned short As[2][256 * 64];
  __shared__ alignas(16) unsigned short Bs0[2][128 * 64];
  __shared__ alignas(16) unsigned short Bs1[DUAL ? 2 : 1][DUAL ? 128 * 64 : 8];

  const int tid = threadIdx.x;
  const int l = tid & 63, w = tid >> 6;
  const int wr = w >> 2, wc = w & 3;
  const int lr = l & 15, lg = l >> 4;

  int m0, n0;
  xcd_map(128, m0, n0);

  const int NT = K >> 6;

  f32x4 acc0[8][2];
  f32x4 acc1[DUAL ? 8 : 1][DUAL ? 2 : 1];
  const f32x4 z4 = {0.f, 0.f, 0.f, 0.f};
#pragma unroll
  for (int i = 0; i < 8; ++i)
#pragma unroll
    for (int j = 0; j < 2; ++j) acc0[i][j] = z4;
  if (DUAL) {
#pragma unroll
    for (int i = 0; i < 8; ++i)
#pragma unroll
      for (int j = 0; j < 2; ++j) acc1[i][j] = z4;
  }

  // prologue
  stage_half(A, lda, m0, 0, 0, As[0], tid);
  stage_half(A, lda, m0, 0, 1, As[0], tid);
  stage_half(B0, K, n0, 0, 0, Bs0[0], tid);
  if (DUAL) stage_half(B1, K, n0, 0, 0, Bs1[0], tid);
  if (NT > 1) {
    stage_half(B0, K, n0, 64, 0, Bs0[1], tid);
    if (DUAL) stage_half(B1, K, n0, 64, 0, Bs1[1], tid);
    stage_half(A, lda, m0, 64, 0, As[1], tid);
    if (DUAL) asm volatile("s_waitcnt vmcnt(6)" ::: "memory");
    else      asm volatile("s_waitcnt vmcnt(4)" ::: "memory");
  } else {
    asm volatile("s_waitcnt vmcnt(0)" ::: "memory");
  }
  __builtin_amdgcn_s_barrier();

  for (int t = 0; t < NT; ++t) {
    const int cur = t & 1;
    const unsigned short* Ac = As[cur];
    const unsigned short* Bc0 = Bs0[cur];
    bf16x8 a0[4][2], a1[4][2], b0f[2][2], b1f[DUAL ? 2 : 1][DUAL ? 2 : 1];

    // ---- c1: issue a0(8)+b0(4) [+b1(4) if DUAL]; stage A-h1(t+1)->nxt ----
#pragma unroll
    for (int i = 0; i < 4; ++i)
#pragma unroll
      for (int kk = 0; kk < 2; ++kk)
        a0[i][kk] = ldsrd(Ac, wr * 128 + i * 16 + lr, kk * 4 + lg);
#pragma unroll
    for (int j = 0; j < 2; ++j)
#pragma unroll
      for (int kk = 0; kk < 2; ++kk)
        b0f[j][kk] = ldsrd(Bc0, wc * 32 + j * 16 + lr, kk * 4 + lg);
    if (t + 1 < NT) stage_half(A, lda, m0, (t + 1) * 64, 1, As[cur ^ 1], tid);
    if (DUAL) {
#pragma unroll
      for (int j = 0; j < 2; ++j)
#pragma unroll
        for (int kk = 0; kk < 2; ++kk)
          b1f[j][kk] = ldsrd(Bs1[cur], wc * 32 + j * 16 + lr, kk * 4 + lg);
    }

    if (DUAL) {
      // ---- c1 MFMA: acc0 = a0 x b0 (b1 drains underneath) ----
      __builtin_amdgcn_s_setprio(1);
#pragma unroll
      for (int i = 0; i < 4; ++i)
#pragma unroll
        for (int j = 0; j < 2; ++j)
#pragma unroll
          for (int kk = 0; kk < 2; ++kk)
            acc0[i][j] = __builtin_amdgcn_mfma_f32_16x16x32_bf16(a0[i][kk], b0f[j][kk], acc0[i][j], 0, 0, 0);
      __builtin_amdgcn_s_setprio(0);
      __builtin_amdgcn_s_barrier();

      // ---- c2: stage B0(t+2)->cur (b0 drained pre-c1 + barrier); acc1 = a0 x b1;
      //          a1[i] issued as a0[i] dies ----
      if (t + 2 < NT) stage_half(B0, K, n0, (t + 2) * 64, 0, Bs0[cur], tid);
      __builtin_amdgcn_s_setprio(1);
#pragma unroll
      for (int i = 0; i < 4; ++i) {
#pragma unroll
        for (int j = 0; j < 2; ++j)
#pragma unroll
          for (int kk = 0; kk < 2; ++kk)
            acc1[i][j] = __builtin_amdgcn_mfma_f32_16x16x32_bf16(a0[i][kk], b1f[j][kk], acc1[i][j], 0, 0, 0);
#pragma unroll
        for (int kk = 0; kk < 2; ++kk)
          a1[i][kk] = ldsrd(Ac, wr * 128 + 64 + i * 16 + lr, kk * 4 + lg);
      }
      __builtin_amdgcn_s_setprio(0);
      __builtin_amdgcn_s_barrier();

      // ---- c3: stage B1(t+2)->cur (b1 drained pre-c2 + barrier); acc0 = a1 x b0 ----
      if (t + 2 < NT) stage_half(B1, K, n0, (t + 2) * 64, 0, Bs1[cur], tid);
      __builtin_amdgcn_s_setprio(1);
#pragma unroll
      for (int i = 0; i < 4; ++i)
#pragma unroll
        for (int j = 0; j < 2; ++j)
#pragma unroll
          for (int kk = 0; kk < 2; ++kk)
            acc0[i + 4][j] = __builtin_amdgcn_mfma_f32_16x16x32_bf16(a1[i][kk], b0f[j][kk], acc0[i + 4][j], 0, 0, 0);
      __builtin_amdgcn_s_setprio(0);
      __builtin_amdgcn_s_barrier();

      // ---- c4: stage A-h0(t+2)->cur (a1 drained pre-c3 + barrier); acc1 = a1 x b1 ----
      if (t + 2 < NT) stage_half(A, lda, m0, (t + 2) * 64, 0, As[cur], tid);
      __builtin_amdgcn_s_setprio(1);
#pragma unroll
      for (int i = 0; i < 4; ++i)
#pragma unroll
        for (int j = 0; j < 2; ++j)
#pragma unroll
          for (int kk = 0; kk < 2; ++kk)
            acc1[i + 4][j] = __builtin_amdgcn_mfma_f32_16x16x32_bf16(a1[i][kk], b1f[j][kk], acc1[i + 4][j], 0, 0, 0);
      __builtin_amdgcn_s_setprio(0);
      if (t + 2 < NT) asm volatile("s_waitcnt vmcnt(6)" ::: "memory");
      else            asm volatile("s_waitcnt vmcnt(0)" ::: "memory");
      __builtin_amdgcn_s_barrier();
    } else {
      // ---- c1 MFMA: acc0 = a0 x b0; a1[i] issued as a0[i] dies ----
      __builtin_amdgcn_s_setprio(1);
#pragma unroll
      for (int i = 0; i < 4; ++i) {
#pragma unroll
        for (int j = 0; j < 2; ++j)
#pragma unroll
          for (int kk = 0; kk < 2; ++kk)
            acc0[i][j] = __builtin_amdgcn_mfma_f32_16x16x32_bf16(a0[i][kk], b0f[j][kk], acc0[i][j], 0, 0, 0);
#pragma unroll
        for (int kk = 0; kk < 2; ++kk)
          a1[i][kk] = ldsrd(Ac, wr * 128 + 64 + i * 16 + lr, kk * 4 + lg);
      }
      __builtin_amdgcn_s_setprio(0);
      __builtin_amdgcn_s_barrier();

      // ---- c2: stage B0(t+2)->cur; drain a1 (own wave, issued back in c1 ->
      //          wide margin), then stage A-h0(t+2)->cur; acc0 = a1 x b0 ----
      if (t + 2 < NT) stage_half(B0, K, n0, (t + 2) * 64, 0, Bs0[cur], tid);
      asm volatile("s_waitcnt lgkmcnt(0)" ::: "memory");
      if (t + 2 < NT) stage_half(A, lda, m0, (t + 2) * 64, 0, As[cur], tid);
      __builtin_amdgcn_s_setprio(1);
#pragma unroll
      for (int i = 0; i < 4; ++i)
#pragma unroll
        for (int j = 0; j < 2; ++j)
#pragma unroll
          for (int kk = 0; kk < 2; ++kk)
            acc0[i + 4][j] = __builtin_amdgcn_mfma_f32_16x16x32_bf16(a1[i][kk], b0f[j][kk], acc0[i + 4][j], 0, 0, 0);
      __builtin_amdgcn_s_setprio(0);
      if (t + 2 < NT) asm volatile("s_waitcnt vmcnt(4)" ::: "memory");
      else            asm volatile("s_waitcnt vmcnt(0)" ::: "memory");
      __builtin_amdgcn_s_barrier();
    }
  }

  // epilogue
#pragma unroll
  for (int i = 0; i < 8; ++i) {
    int r0 = m0 + wr * 128 + i * 16 + lg * 4;
#pragma unroll
    for (int j = 0; j < 2; ++j) {
      int col = n0 + wc * 32 + j * 16 + lr;
      float bb0 = bias0[col];
#pragma unroll
      for (int q = 0; q < 4; ++q) {
        size_t off = (size_t)(r0 + q) * ldc + col;
        float v = acc0[i][j][q] + bb0;
        if (MODE == 1) {
          ((float*)out)[off] = v + ((const float*)resg)[off];
        } else {
          float gt = acc1[i][j][q] + bias1[col];
          ((unsigned short*)out)[off] = f2bf(v * (gt / (1.f + expf(-gt))));
        }
      }
    }
  }
}

// ---------- flash attention: paired q-tiles, T14 reg-prefetch, exp2 softmax ----
__global__ __launch_bounds__(256, 3)
void attn_kernel(const unsigned short* __restrict__ qkv,
                 const unsigned short* __restrict__ vT,
                 unsigned short* __restrict__ ctx) {
  __shared__ unsigned short Ks[64 * 128];
  __shared__ unsigned short Vs[128 * 64];
  __shared__ unsigned short Ps[4][16 * 80];

  const int pid = blockIdx.x, bh = blockIdx.y;
  const int b = bh >> 4, h = bh & 15;
  const int tid = threadIdx.x, l = tid & 63, w = tid >> 6;
  const int lr = l & 15, lg = l >> 4;
  const float slope2 = exp2f(-0.5f * (float)(h + 1)) * 1.44269504f;
  const float SC2 = 0.0078125f * 1.44269504f;

  const int krow = tid >> 4, kcb = tid & 15;
  const int vrow = tid >> 3, vcb = tid & 7;
  const unsigned short* kbase = qkv + (size_t)(b * 2048 + krow) * 6144 + 2048 + h * 128 + kcb * 8;
  const unsigned short* vbase = vT + (size_t)(bh * 128 + vrow) * 2048 + vcb * 8;
  char* kdst = (char*)Ks + krow * 256 + ((kcb ^ (krow & 7)) << 4);
  char* vdst = (char*)Vs + vrow * 128 + ((vcb ^ (vrow & 7)) << 4);

  int4 kr[4], vr[4];
#pragma unroll
  for (int p = 0; p < 4; ++p) {
    kr[p] = *(const int4*)(kbase + (size_t)p * 16 * 6144);
    vr[p] = *(const int4*)(vbase + (size_t)p * 32 * 2048);
  }

  for (int tq = 0; tq < 2; ++tq) {
    const int qb = tq ? (31 - pid) : pid;
    const int q0 = qb * 64;
    bf16x8 aq[4];
    {
      const unsigned short* qp =
          qkv + (size_t)(b * 2048 + q0 + w * 16 + lr) * 6144 + h * 128 + lg * 8;
#pragma unroll
      for (int kk = 0; kk < 4; ++kk) aq[kk] = *(const bf16x8*)(qp + kk * 32);
    }
    const f32x4 z4 = {0.f, 0.f, 0.f, 0.f};
    f32x4 acc[8];
#pragma unroll
    for (int dt = 0; dt < 8; ++dt) acc[dt] = z4;
    float m_r[4] = {-INFINITY, -INFINITY, -INFINITY, -INFINITY};
    float l_r[4] = {0.f, 0.f, 0.f, 0.f};
    const int ibase = q0 + w * 16 + lg * 4;
    const int nc = qb + 1;

    for (int c = 0; c < nc; ++c) {
      const int kv0 = c * 64;
      __syncthreads();
#pragma unroll
      for (int p = 0; p < 4; ++p) {
        *(int4*)(kdst + p * 4096) = kr[p];
        *(int4*)(vdst + p * 4096) = vr[p];
      }
      __syncthreads();
      {
        int nxt = (c + 1 < nc) ? (c + 1) * 64 : (tq == 0 ? 0 : -1);
        if (nxt >= 0) {
#pragma unroll
          for (int p = 0; p < 4; ++p) {
            kr[p] = *(const int4*)(kbase + (size_t)nxt * 6144 + (size_t)p * 16 * 6144);
            vr[p] = *(const int4*)(vbase + nxt + (size_t)p * 32 * 2048);
          }
        }
      }

      f32x4 sc[4];
#pragma unroll
      for (int t = 0; t < 4; ++t) sc[t] = z4;
      __builtin_amdgcn_s_setprio(1);
#pragma unroll
      for (int t = 0; t < 4; ++t) {
#pragma unroll
        for (int kk = 0; kk < 4; ++kk) {
          int row = t * 16 + lr;
          int bo = (row * 256 + kk * 64 + lg * 16) ^ ((row & 7) << 4);
          bf16x8 bk = *(const bf16x8*)((const char*)Ks + bo);
          sc[t] = __builtin_amdgcn_mfma_f32_16x16x32_bf16(aq[kk], bk, sc[t], 0, 0, 0);
        }
      }
      __builtin_amdgcn_s_setprio(0);
      float cmax[4] = {-INFINITY, -INFINITY, -INFINITY, -INFINITY};
#pragma unroll
      for (int t = 0; t < 4; ++t)
#pragma unroll
        for (int q = 0; q < 4; ++q) {
          int j = kv0 + t * 16 + lr;
          int i = ibase + q;
          float s = sc[t][q] * SC2 + slope2 * (float)(j - i);
          if (j > i) s = -1e9f;
          sc[t][q] = s;
          cmax[q] = fmaxf(cmax[q], s);
        }
#pragma unroll
      for (int q = 0; q < 4; ++q) {
        float v = cmax[q];
        v = fmaxf(v, __shfl_xor(v, 1));
        v = fmaxf(v, __shfl_xor(v, 2));
        v = fmaxf(v, __shfl_xor(v, 4));
        v = fmaxf(v, __shfl_xor(v, 8));
        cmax[q] = v;
      }
      float alpha[4], rsum[4];
#pragma unroll
      for (int q = 0; q < 4; ++q) {
        float mn = fmaxf(m_r[q], cmax[q]);
        alpha[q] = exp2f(m_r[q] - mn);
        m_r[q] = mn;
        rsum[q] = 0.f;
      }
#pragma unroll
      for (int t = 0; t < 4; ++t)
#pragma unroll
        for (int q = 0; q < 4; ++q) {
          float p = exp2f(sc[t][q] - m_r[q]);
          rsum[q] += p;
          sc[t][q] = p;
        }
#pragma unroll
      for (int q = 0; q < 4; ++q) {
        float v = rsum[q];
        v += __shfl_xor(v, 1);
        v += __shfl_xor(v, 2);
        v += __shfl_xor(v, 4);
        v += __shfl_xor(v, 8);
        l_r[q] = l_r[q] * alpha[q] + v;
      }
#pragma unroll
      for (int dt = 0; dt < 8; ++dt)
#pragma unroll
        for (int q = 0; q < 4; ++q) acc[dt][q] *= alpha[q];
#pragma unroll
      for (int t = 0; t < 4; ++t)
#pragma unroll
        for (int q = 0; q < 4; ++q)
          Ps[w][(lg * 4 + q) * 80 + t * 16 + lr] = f2bf(sc[t][q]);
      __builtin_amdgcn_s_setprio(1);
#pragma unroll
      for (int kc = 0; kc < 2; ++kc) {
        bf16x8 ap = *(const bf16x8*)(&Ps[w][lr * 80 + kc * 32 + lg * 8]);
#pragma unroll
        for (int dt = 0; dt < 8; ++dt) {
          int row = dt * 16 + lr;
          int bo = (row * 128 + kc * 64 + lg * 16) ^ ((row & 7) << 4);
          bf16x8 bv = *(const bf16x8*)((const char*)Vs + bo);
          acc[dt] = __builtin_amdgcn_mfma_f32_16x16x32_bf16(ap, bv, acc[dt], 0, 0, 0);
        }
      }
      __builtin_amdgcn_s_setprio(0);
    }
#pragma unroll
    for (int q = 0; q < 4; ++q) {
      float inv = 1.f / l_r[q];
      int row = ibase + q;
#pragma unroll
      for (int dt = 0; dt < 8; ++dt)
        ctx[(size_t)(b * 2048 + row) * 2048 + h * 128 + dt * 16 + lr] =
            f2bf(acc[dt][q] * inv);
    }
  }
}

// ---------- launch ----------
extern "C" void kernel_launch(void* const* d_in, const int* in_sizes, int n_in,
                              void* d_out, int out_size, void* d_ws, size_t ws_size,
                              hipStream_t stream) {
  const float* hs   = (const float*)d_in[0];
  const float* ln1g = (const float*)d_in[3];
  const float* ln1b = (const float*)d_in[4];
  const float* wqkv = (const float*)d_in[5];
  const float* bqkv = (const float*)d_in[6];
  const float* wo   = (const float*)d_in[7];
  const float* bo   = (const float*)d_in[8];
  const float* ln2g = (const float*)d_in[9];
  const float* ln2b = (const float*)d_in[10];
  const float* wfc  = (const float*)d_in[11];
  const float* bfc  = (const float*)d_in[12];
  const float* wfc2 = (const float*)d_in[13];
  const float* bfc2 = (const float*)d_in[14];
  const float* wpj  = (const float*)d_in[15];
  const float* bpj  = (const float*)d_in[16];

  char* ws = (char*)d_ws;
  unsigned short* woT   = (unsigned short*)(ws + 0);          //  8 MB
  unsigned short* wfcT  = (unsigned short*)(ws + 8388608);    // 24 MB
  unsigned short* wfc2T = (unsigned short*)(ws + 33554432);   // 24 MB
  unsigned short* hbuf  = (unsigned short*)(ws + 58720256);   // 16 MB
  unsigned short* qkvb  = (unsigned short*)(ws + 75497472);   // 48 MB (later mlp_in)
  unsigned short* wqkvT = (unsigned short*)(ws + 125829120);  // 24 MB (later wpjT)
  unsigned short* vTb   = (unsigned short*)(ws + 150994944);  // 16 MB
  unsigned short* ctxb  = (unsigned short*)(ws + 167772160);  // 16 MB
  unsigned short* wpjT  = wqkvT;
  float* outf = (float*)d_out;

  dim3 blk(256), blk512(512);
  transpose_cast_f32<<<dim3(96, 32), blk, 0, stream>>>(wqkv, wqkvT, 2048, 6144);
  transpose_cast_f32<<<dim3(32, 32), blk, 0, stream>>>(wo, woT, 2048, 2048);
  transpose_cast_f32<<<dim3(96, 32), blk, 0, stream>>>(wfc, wfcT, 2048, 6144);
  transpose_cast_f32<<<dim3(96, 32), blk, 0, stream>>>(wfc2, wfc2T, 2048, 6144);
  ln_kernel<<<dim3(4096), blk, 0, stream>>>(hs, ln1g, ln1b, hbuf);
  // QKV: [4096,2048] x [6144,2048]^T -> [4096,6144] bf16
  gemm256<0><<<dim3(24, 16), blk512, 0, stream>>>(hbuf, 2048, wqkvT, bqkv, nullptr,
                                                  qkvb, 6144, 2048);
  transpose_v<<<dim3(32, 2, 32), blk, 0, stream>>>(qkvb, vTb);
  transpose_cast_f32<<<dim3(32, 96), blk, 0, stream>>>(wpj, wpjT, 6144, 2048);
  // attention (paired q-tiles)
  attn_kernel<<<dim3(16, 32), blk, 0, stream>>>(qkvb, vTb, ctxb);
  // O-proj + residual -> d_out f32  (grid 256 = full GPU)
  gemm_n128<1, false><<<dim3(16, 16), blk512, 0, stream>>>(
      ctxb, 2048, woT, nullptr, bo, nullptr, hs, d_out, 2048, 2048);
  ln_kernel<<<dim3(4096), blk, 0, stream>>>(outf, ln2g, ln2b, hbuf);
  // fused MLP gate/up: out = (h2@wfc + bfc) * silu(h2@wfc2 + bfc2)
  gemm_n128<2, true><<<dim3(48, 16), blk512, 0, stream>>>(
      hbuf, 2048, wfcT, wfc2T, bfc, bfc2, nullptr, qkvb, 6144, 2048);
  // proj + residual -> d_out
  gemm_n128<1, false><<<dim3(16, 16), blk512, 0, stream>>>(
      qkvb, 6144, wpjT, nullptr, bpj, nullptr, outf, d_out, 2048, 6144);
}

// Round 2
// 775.759 us; speedup vs baseline: 1.0315x; 1.0300x over previous
//
#include <hip/hip_runtime.h>
#include <hip/hip_bf16.h>
#include <math.h>

#define DI __device__ __forceinline__

typedef __bf16 bf16x8 __attribute__((ext_vector_type(8)));
typedef float f32x4 __attribute__((ext_vector_type(4)));
typedef short s16x8 __attribute__((ext_vector_type(8)));

// ---------- helpers ----------
DI unsigned short f2bf(float f) {
  unsigned int u = __builtin_bit_cast(unsigned int, f);
  unsigned int r = (u + 0x7fffu + ((u >> 16) & 1u)) >> 16;
  return (unsigned short)r;
}
DI float bf2f(unsigned short h) {
  unsigned int u = ((unsigned int)h) << 16;
  return __builtin_bit_cast(float, u);
}

DI void gload16(const void* g, void* l) {
  __builtin_amdgcn_global_load_lds(
      (const __attribute__((address_space(1))) void*)g,
      (__attribute__((address_space(3))) void*)l, 16, 0, 0);
}

DI unsigned ldsoff(const void* p) {
  return (unsigned)(size_t)(const __attribute__((address_space(3))) void*)p;
}

// asm ds_read_b128 with compile-time offset: compiler cannot sink/elide it, so
// prefetched fragments stay issued where we put them (the compiler was sinking
// source-level hoisted reads to limit register liveness -> serial phases).
template <int OFF>
DI bf16x8 ds128(unsigned base) {
  bf16x8 r;
  asm volatile("ds_read_b128 %0, %1 offset:%2" : "=v"(r) : "v"(base), "i"(OFF));
  return r;
}
// counted waits + sched_barrier(0) (rule: MFMA intrinsics can hoist past bare
// inline-asm waitcnt; the sched_barrier pins them below).
template <int N>
DI void lgkm() {
  asm volatile("s_waitcnt lgkmcnt(%0)" ::"i"(N));
  __builtin_amdgcn_sched_barrier(0);
}
template <int N>
DI void vmc() {
  asm volatile("s_waitcnt vmcnt(%0)" ::"i"(N));
  __builtin_amdgcn_sched_barrier(0);
}

// 2-D XCD rasterization: XCD grid 2(m) x 4(n); within an XCD, m-fastest so the
// ~32 co-resident blocks form an 8m x 4n rectangle (L2 panel reuse). ny == 16.
DI void xcd_map(int BN, int& m0, int& n0) {
  const int nx = gridDim.x;
  int orig = blockIdx.y * nx + blockIdx.x;
  int xcd = orig & 7, k = orig >> 3;
  int xm = xcd >> 2, xn = xcd & 3;
  int nband = nx >> 2;
  m0 = (xm * 8 + (k & 7)) * 256;
  n0 = (xn * nband + (k >> 3)) * BN;
}

// ---------- transpose + fp32->bf16 cast: out[c][r] = bf16(in[r][c]) ----------
__global__ __launch_bounds__(256)
void transpose_cast_f32(const float* __restrict__ in, unsigned short* __restrict__ out,
                        int R, int C) {
  __shared__ unsigned int t[64 * 65];
  const int r0 = blockIdx.y * 64, c0 = blockIdx.x * 64;
  const int tid = threadIdx.x;
#pragma unroll
  for (int p = 0; p < 4; ++p) {
    int e = p * 1024 + tid * 4;
    int r = e >> 6, c = e & 63;
    float4 v = *(const float4*)(in + (size_t)(r0 + r) * C + c0 + c);
    t[r * 65 + c + 0] = f2bf(v.x);
    t[r * 65 + c + 1] = f2bf(v.y);
    t[r * 65 + c + 2] = f2bf(v.z);
    t[r * 65 + c + 3] = f2bf(v.w);
  }
  __syncthreads();
  const int oc = tid >> 2, ch = tid & 3;
  alignas(16) unsigned short vals[16];
#pragma unroll
  for (int j = 0; j < 16; ++j) vals[j] = (unsigned short)t[(ch * 16 + j) * 65 + oc];
  size_t ob = (size_t)(c0 + oc) * R + r0 + ch * 16;
  *(s16x8*)(out + ob) = *(const s16x8*)(vals);
  *(s16x8*)(out + ob + 8) = *(const s16x8*)(vals + 8);
}

// ---------- V transpose: qkv[b][s][4096+h*128+d] -> vT[bh][d][s] (bf16) ----------
__global__ __launch_bounds__(256)
void transpose_v(const unsigned short* __restrict__ qkv, unsigned short* __restrict__ vT) {
  __shared__ unsigned int t[64 * 65];
  const int s0 = blockIdx.x * 64, d0 = blockIdx.y * 64, bh = blockIdx.z;
  const int b = bh >> 4, h = bh & 15;
  const int tid = threadIdx.x;
#pragma unroll
  for (int p = 0; p < 2; ++p) {
    int id = p * 256 + tid;
    int r = id >> 3, c = (id & 7) * 8;
    s16x8 v = *(const s16x8*)(qkv + (size_t)(b * 2048 + s0 + r) * 6144 + 4096 + h * 128 + d0 + c);
#pragma unroll
    for (int j = 0; j < 8; ++j) t[r * 65 + c + j] = (unsigned short)((const unsigned short*)&v)[j];
  }
  __syncthreads();
  const int oc = tid >> 2, ch = tid & 3;
  alignas(16) unsigned short vals[16];
#pragma unroll
  for (int j = 0; j < 16; ++j) vals[j] = (unsigned short)t[(ch * 16 + j) * 65 + oc];
  size_t ob = (size_t)(bh * 128 + d0 + oc) * 2048 + s0 + ch * 16;
  *(s16x8*)(vT + ob) = *(const s16x8*)(vals);
  *(s16x8*)(vT + ob + 8) = *(const s16x8*)(vals + 8);
}

// ---------- LayerNorm fp32 -> bf16, row = 2048 ----------
__global__ __launch_bounds__(256)
void ln_kernel(const float* __restrict__ x, const float* __restrict__ g,
               const float* __restrict__ bi, unsigned short* __restrict__ y) {
  __shared__ float red[8];
  const int row = blockIdx.x, tid = threadIdx.x;
  const float* xp = x + (size_t)row * 2048 + tid * 8;
  float4 v0 = *(const float4*)xp;
  float4 v1 = *(const float4*)(xp + 4);
  float v[8] = {v0.x, v0.y, v0.z, v0.w, v1.x, v1.y, v1.z, v1.w};
  float s = 0.f;
#pragma unroll
  for (int j = 0; j < 8; ++j) s += v[j];
#pragma unroll
  for (int d = 1; d < 64; d <<= 1) s += __shfl_xor(s, d);
  if ((tid & 63) == 0) red[tid >> 6] = s;
  __syncthreads();
  float mean = (red[0] + red[1] + red[2] + red[3]) * (1.f / 2048.f);
  float dd[8], sq = 0.f;
#pragma unroll
  for (int j = 0; j < 8; ++j) { dd[j] = v[j] - mean; sq += dd[j] * dd[j]; }
#pragma unroll
  for (int d = 1; d < 64; d <<= 1) sq += __shfl_xor(sq, d);
  if ((tid & 63) == 0) red[4 + (tid >> 6)] = sq;
  __syncthreads();
  float var = (red[4] + red[5] + red[6] + red[7]) * (1.f / 2048.f);
  float rs = rsqrtf(var + 1e-5f);
  float4 g0 = *(const float4*)(g + tid * 8), g1 = *(const float4*)(g + tid * 8 + 4);
  float4 b0 = *(const float4*)(bi + tid * 8), b1 = *(const float4*)(bi + tid * 8 + 4);
  float gg[8] = {g0.x, g0.y, g0.z, g0.w, g1.x, g1.y, g1.z, g1.w};
  float bb[8] = {b0.x, b0.y, b0.z, b0.w, b1.x, b1.y, b1.z, b1.w};
  alignas(16) unsigned short o[8];
#pragma unroll
  for (int j = 0; j < 8; ++j) o[j] = f2bf(dd[j] * rs * gg[j] + bb[j]);
  *(s16x8*)(y + (size_t)row * 2048 + tid * 8) = *(const s16x8*)o;
}

// ---------- shared GEMM staging helpers ----------
DI void stage_half(const unsigned short* __restrict__ G, int ld, int rbase, int kt,
                   int h, unsigned short* dst, int tid) {
#pragma unroll
  for (int i = 0; i < 2; ++i) {
    int id = i * 512 + tid;
    int rl = id >> 3, sl = id & 7;
    int ss = sl ^ (rl & 7);
    gload16(G + (size_t)(rbase + h * 128 + rl) * ld + kt + ss * 8,
            (char*)dst + h * 16384 + id * 16);
  }
}

DI bf16x8 ldsrd(const unsigned short* buf, int row, int ks) {
  return *(const bf16x8*)((const char*)buf + row * 128 + ((ks ^ (row & 7)) << 4));
}

// ---------- 256x256 GEMM, 4 clusters/K-tile, read-hoisted schedule ----------
// MODE 0: out bf16 = acc + bias ; MODE 1: out f32 = acc + bias + res
template <int MODE>
__global__ __launch_bounds__(512, 2)
void gemm256(const unsigned short* __restrict__ A, int lda,
             const unsigned short* __restrict__ B,
             const float* __restrict__ bias,
             const void* __restrict__ resg,
             void* __restrict__ out, int ldc, int K) {
  __shared__ alignas(16) unsigned short As[2][256 * 64];
  __shared__ alignas(16) unsigned short Bs[2][256 * 64];

  const int tid = threadIdx.x;
  const int l = tid & 63, w = tid >> 6;
  const int wr = w >> 2, wc = w & 3;
  const int lr = l & 15, lg = l >> 4;

  int m0, n0;
  xcd_map(256, m0, n0);

  const int NT = K >> 6;

  f32x4 acc[8][4];
  const f32x4 z4 = {0.f, 0.f, 0.f, 0.f};
#pragma unroll
  for (int i = 0; i < 8; ++i)
#pragma unroll
    for (int j = 0; j < 4; ++j) acc[i][j] = z4;

  stage_half(A, lda, m0, 0, 0, As[0], tid);
  stage_half(A, lda, m0, 0, 1, As[0], tid);
  stage_half(B, K, n0, 0, 0, Bs[0], tid);
  stage_half(B, K, n0, 0, 1, Bs[0], tid);
  if (NT > 1) {
    stage_half(B, K, n0, 64, 0, Bs[1], tid);
    stage_half(B, K, n0, 64, 1, Bs[1], tid);
    stage_half(A, lda, m0, 64, 0, As[1], tid);
    asm volatile("s_waitcnt vmcnt(6)" ::: "memory");
  } else {
    asm volatile("s_waitcnt vmcnt(0)" ::: "memory");
  }
  __builtin_amdgcn_s_barrier();

  for (int t = 0; t < NT; ++t) {
    const int cur = t & 1;
    const unsigned short* Ac = As[cur];
    const unsigned short* Bc = Bs[cur];
    bf16x8 a0[4][2], a1[4][2], bfr[4][2];

    // ---- c1: issue a0(8)+b0123(8); stage A-h1(t+1)->nxt; Q1 = a0 x b01 ----
#pragma unroll
    for (int i = 0; i < 4; ++i)
#pragma unroll
      for (int kk = 0; kk < 2; ++kk)
        a0[i][kk] = ldsrd(Ac, wr * 128 + i * 16 + lr, kk * 4 + lg);
#pragma unroll
    for (int j = 0; j < 2; ++j)
#pragma unroll
      for (int kk = 0; kk < 2; ++kk)
        bfr[j][kk] = ldsrd(Bc, wc * 64 + j * 16 + lr, kk * 4 + lg);
    if (t + 1 < NT) stage_half(A, lda, m0, (t + 1) * 64, 1, As[cur ^ 1], tid);
#pragma unroll
    for (int j = 2; j < 4; ++j)
#pragma unroll
      for (int kk = 0; kk < 2; ++kk)
        bfr[j][kk] = ldsrd(Bc, wc * 64 + j * 16 + lr, kk * 4 + lg);
    __builtin_amdgcn_s_setprio(1);
#pragma unroll
    for (int i = 0; i < 4; ++i)
#pragma unroll
      for (int j = 0; j < 2; ++j)
#pragma unroll
        for (int kk = 0; kk < 2; ++kk)
          acc[i][j] = __builtin_amdgcn_mfma_f32_16x16x32_bf16(a0[i][kk], bfr[j][kk], acc[i][j], 0, 0, 0);
    __builtin_amdgcn_s_setprio(0);
    __builtin_amdgcn_s_barrier();

    // ---- c2: Q2 = a0 x b23; a1 issued under the MFMAs ----
    __builtin_amdgcn_s_setprio(1);
#pragma unroll
    for (int i = 0; i < 4; ++i) {
#pragma unroll
      for (int j = 2; j < 4; ++j)
#pragma unroll
        for (int kk = 0; kk < 2; ++kk)
          acc[i][j] = __builtin_amdgcn_mfma_f32_16x16x32_bf16(a0[i][kk], bfr[j][kk], acc[i][j], 0, 0, 0);
#pragma unroll
      for (int kk = 0; kk < 2; ++kk)
        a1[i][kk] = ldsrd(Ac, wr * 128 + 64 + i * 16 + lr, kk * 4 + lg);
    }
    __builtin_amdgcn_s_setprio(0);
    __builtin_amdgcn_s_barrier();

    // ---- c3: stage B-h0(t+2)->cur; Q3 ----
    if (t + 2 < NT) stage_half(B, K, n0, (t + 2) * 64, 0, Bs[cur], tid);
    __builtin_amdgcn_s_setprio(1);
#pragma unroll
    for (int i = 0; i < 4; ++i)
#pragma unroll
      for (int j = 0; j < 2; ++j)
#pragma unroll
        for (int kk = 0; kk < 2; ++kk)
          acc[i + 4][j] = __builtin_amdgcn_mfma_f32_16x16x32_bf16(a1[i][kk], bfr[j][kk], acc[i + 4][j], 0, 0, 0);
    __builtin_amdgcn_s_setprio(0);
    __builtin_amdgcn_s_barrier();

    // ---- c4: stage B-h1(t+2)+A-h0(t+2)->cur; Q4 ----
    if (t + 2 < NT) {
      stage_half(B, K, n0, (t + 2) * 64, 1, Bs[cur], tid);
      stage_half(A, lda, m0, (t + 2) * 64, 0, As[cur], tid);
    }
    __builtin_amdgcn_s_setprio(1);
#pragma unroll
    for (int i = 0; i < 4; ++i)
#pragma unroll
      for (int j = 2; j < 4; ++j)
#pragma unroll
        for (int kk = 0; kk < 2; ++kk)
          acc[i + 4][j] = __builtin_amdgcn_mfma_f32_16x16x32_bf16(a1[i][kk], bfr[j][kk], acc[i + 4][j], 0, 0, 0);
    __builtin_amdgcn_s_setprio(0);
    if (t + 2 < NT) {
      asm volatile("s_waitcnt vmcnt(6)" ::: "memory");
    } else {
      asm volatile("s_waitcnt vmcnt(0)" ::: "memory");
    }
    __builtin_amdgcn_s_barrier();
  }

#pragma unroll
  for (int i = 0; i < 8; ++i) {
    int r0 = m0 + wr * 128 + i * 16 + lg * 4;
#pragma unroll
    for (int j = 0; j < 4; ++j) {
      int col = n0 + wc * 64 + j * 16 + lr;
      float bb = bias[col];
#pragma unroll
      for (int q = 0; q < 4; ++q) {
        size_t off = (size_t)(r0 + q) * ldc + col;
        float v = acc[i][j][q] + bb;
        if (MODE == 0) {
          ((unsigned short*)out)[off] = f2bf(v);
        } else {
          ((float*)out)[off] = v + ((const float*)resg)[off];
        }
      }
    }
  }
}

// ---------- 256x128 GEMM, single-B (2-cluster) ----------
// MODE 1: out f32 = acc0 + bias0 + res
template <int MODE, bool DUAL>
__global__ __launch_bounds__(512, 2)
void gemm_n128(const unsigned short* __restrict__ A, int lda,
               const unsigned short* __restrict__ B0,
               const unsigned short* __restrict__ B1,
               const float* __restrict__ bias0, const float* __restrict__ bias1,
               const void* __restrict__ resg,
               void* __restrict__ out, int ldc, int K) {
  __shared__ alignas(16) unsigned short As[2][256 * 64];
  __shared__ alignas(16) unsigned short Bs0[2][128 * 64];

  const int tid = threadIdx.x;
  const int l = tid & 63, w = tid >> 6;
  const int wr = w >> 2, wc = w & 3;
  const int lr = l & 15, lg = l >> 4;

  int m0, n0;
  xcd_map(128, m0, n0);

  const int NT = K >> 6;

  f32x4 acc0[8][2];
  const f32x4 z4 = {0.f, 0.f, 0.f, 0.f};
#pragma unroll
  for (int i = 0; i < 8; ++i)
#pragma unroll
    for (int j = 0; j < 2; ++j) acc0[i][j] = z4;

  // prologue
  stage_half(A, lda, m0, 0, 0, As[0], tid);
  stage_half(A, lda, m0, 0, 1, As[0], tid);
  stage_half(B0, K, n0, 0, 0, Bs0[0], tid);
  if (NT > 1) {
    stage_half(B0, K, n0, 64, 0, Bs0[1], tid);
    stage_half(A, lda, m0, 64, 0, As[1], tid);
    asm volatile("s_waitcnt vmcnt(4)" ::: "memory");
  } else {
    asm volatile("s_waitcnt vmcnt(0)" ::: "memory");
  }
  __builtin_amdgcn_s_barrier();

  for (int t = 0; t < NT; ++t) {
    const int cur = t & 1;
    const unsigned short* Ac = As[cur];
    const unsigned short* Bc0 = Bs0[cur];
    bf16x8 a0[4][2], a1[4][2], b0f[2][2];

    // ---- c1: issue a0(8)+b0(4); stage A-h1(t+1)->nxt; MFMA + a1 issue ----
#pragma unroll
    for (int i = 0; i < 4; ++i)
#pragma unroll
      for (int kk = 0; kk < 2; ++kk)
        a0[i][kk] = ldsrd(Ac, wr * 128 + i * 16 + lr, kk * 4 + lg);
#pragma unroll
    for (int j = 0; j < 2; ++j)
#pragma unroll
      for (int kk = 0; kk < 2; ++kk)
        b0f[j][kk] = ldsrd(Bc0, wc * 32 + j * 16 + lr, kk * 4 + lg);
    if (t + 1 < NT) stage_half(A, lda, m0, (t + 1) * 64, 1, As[cur ^ 1], tid);

    __builtin_amdgcn_s_setprio(1);
#pragma unroll
    for (int i = 0; i < 4; ++i) {
#pragma unroll
      for (int j = 0; j < 2; ++j)
#pragma unroll
        for (int kk = 0; kk < 2; ++kk)
          acc0[i][j] = __builtin_amdgcn_mfma_f32_16x16x32_bf16(a0[i][kk], b0f[j][kk], acc0[i][j], 0, 0, 0);
#pragma unroll
      for (int kk = 0; kk < 2; ++kk)
        a1[i][kk] = ldsrd(Ac, wr * 128 + 64 + i * 16 + lr, kk * 4 + lg);
    }
    __builtin_amdgcn_s_setprio(0);
    __builtin_amdgcn_s_barrier();

    // ---- c2: stage B0(t+2)->cur; drain a1; stage A-h0(t+2)->cur; MFMA ----
    if (t + 2 < NT) stage_half(B0, K, n0, (t + 2) * 64, 0, Bs0[cur], tid);
    asm volatile("s_waitcnt lgkmcnt(0)" ::: "memory");
    if (t + 2 < NT) stage_half(A, lda, m0, (t + 2) * 64, 0, As[cur], tid);
    __builtin_amdgcn_s_setprio(1);
#pragma unroll
    for (int i = 0; i < 4; ++i)
#pragma unroll
      for (int j = 0; j < 2; ++j)
#pragma unroll
        for (int kk = 0; kk < 2; ++kk)
          acc0[i + 4][j] = __builtin_amdgcn_mfma_f32_16x16x32_bf16(a1[i][kk], b0f[j][kk], acc0[i + 4][j], 0, 0, 0);
    __builtin_amdgcn_s_setprio(0);
    if (t + 2 < NT) asm volatile("s_waitcnt vmcnt(4)" ::: "memory");
    else            asm volatile("s_waitcnt vmcnt(0)" ::: "memory");
    __builtin_amdgcn_s_barrier();
  }

  // epilogue
#pragma unroll
  for (int i = 0; i < 8; ++i) {
    int r0 = m0 + wr * 128 + i * 16 + lg * 4;
#pragma unroll
    for (int j = 0; j < 2; ++j) {
      int col = n0 + wc * 32 + j * 16 + lr;
      float bb0 = bias0[col];
#pragma unroll
      for (int q = 0; q < 4; ++q) {
        size_t off = (size_t)(r0 + q) * ldc + col;
        float v = acc0[i][j][q] + bb0;
        ((float*)out)[off] = v + ((const float*)resg)[off];
      }
    }
  }
}

// ---------- MLP dual GEMM: 256x128, counted-wait asm-pipelined 4-phase -------
// Reads for phase p+1 are issued as inline-asm ds_read_b128 before phase p's
// MFMAs; counted lgkmcnt waits drain exactly the prior phase's reads, so the
// just-issued reads stay in flight under the MFMA cluster. One barrier/phase,
// one counted vmcnt(2)/K-step (tile t+1 fully landed by P2-end; tile t+2
// stages in flight). Safety: every stage targets a region whose reads were
// drained by a counted lgkm preceding a barrier; every read targets data
// drained by a vmcnt preceding a barrier.
DI void mmq(f32x4 (&acc)[8][2], int io, const bf16x8 (&af)[4][2], const bf16x8 (&bf)[2][2]) {
#pragma unroll
  for (int kk = 0; kk < 2; ++kk)
#pragma unroll
    for (int i = 0; i < 4; ++i)
#pragma unroll
      for (int j = 0; j < 2; ++j)
        acc[io + i][j] = __builtin_amdgcn_mfma_f32_16x16x32_bf16(af[i][kk], bf[j][kk], acc[io + i][j], 0, 0, 0);
}

#define RDA(dst, B0_, B1_, OFS)                                        \
  dst[0][0] = ds128<(OFS) + 0>(B0_);    dst[0][1] = ds128<(OFS) + 0>(B1_);    \
  dst[1][0] = ds128<(OFS) + 2048>(B0_); dst[1][1] = ds128<(OFS) + 2048>(B1_); \
  dst[2][0] = ds128<(OFS) + 4096>(B0_); dst[2][1] = ds128<(OFS) + 4096>(B1_); \
  dst[3][0] = ds128<(OFS) + 6144>(B0_); dst[3][1] = ds128<(OFS) + 6144>(B1_);

#define RDB(dst, B0_, B1_, OFS)                                        \
  dst[0][0] = ds128<(OFS) + 0>(B0_);    dst[0][1] = ds128<(OFS) + 0>(B1_);    \
  dst[1][0] = ds128<(OFS) + 2048>(B0_); dst[1][1] = ds128<(OFS) + 2048>(B1_);

// A0C/B0C/B1C/A1C: fragments for iter t (A0C/B0C pre-read in t-1).
// A0N/B0N: fragments for iter t+1, issued in P3/P4.
#define MLP_ITER(t, CUR, A0C, B0C, B1C, A1C, A0N, B0N)                         \
  {                                                                            \
    /* P1: issue b1(t); wait a0(t),b0(t); Q1 = a0 x b0 -> acc0 lo */           \
    RDB(B1C, cA0, cA1, (CUR) * 16384);                                         \
    lgkm<4>();                                                                 \
    __builtin_amdgcn_s_setprio(1);                                             \
    mmq(acc0, 0, A0C, B0C);                                                    \
    __builtin_amdgcn_s_setprio(0);                                             \
    __builtin_amdgcn_sched_barrier(0);                                         \
    __builtin_amdgcn_s_barrier();                                              \
    /* P2: stage B0(t+2); issue a1(t); wait b1(t); Q2 = a0 x b1 -> acc1 lo */  \
    if ((t) + 2 < NT) stage_half(B0, K, n0, ((t) + 2) * 64, 0, Bs0[CUR], tid); \
    RDA(A1C, aA0, aA1, (CUR) * 32768 + 8192);                                  \
    lgkm<8>();                                                                 \
    __builtin_amdgcn_s_setprio(1);                                             \
    mmq(acc1, 0, A0C, B1C);                                                    \
    __builtin_amdgcn_s_setprio(0);                                             \
    if ((t) + 2 < NT) { vmc<2>(); } else { vmc<0>(); }                         \
    __builtin_amdgcn_s_barrier();                                              \
    /* P3: stage B1(t+2); issue a0(t+1); wait a1(t); Q3 = a1 x b0 -> acc0 hi */\
    if ((t) + 2 < NT) stage_half(B1, K, n0, ((t) + 2) * 64, 0, Bs1[CUR], tid); \
    RDA(A0N, aA0, aA1, ((CUR) ^ 1) * 32768);                                   \
    lgkm<8>();                                                                 \
    __builtin_amdgcn_s_setprio(1);                                             \
    mmq(acc0, 4, A1C, B0C);                                                    \
    __builtin_amdgcn_s_setprio(0);                                             \
    __builtin_amdgcn_sched_barrier(0);                                         \
    __builtin_amdgcn_s_barrier();                                              \
    /* P4: stage A(t+2) both halves; issue b0(t+1); Q4 = a1 x b1 -> acc1 hi */ \
    if ((t) + 2 < NT) {                                                        \
      stage_half(A, lda, m0, ((t) + 2) * 64, 0, As[CUR], tid);                 \
      stage_half(A, lda, m0, ((t) + 2) * 64, 1, As[CUR], tid);                 \
    }                                                                          \
    RDB(B0N, bA0, bA1, ((CUR) ^ 1) * 16384);                                   \
    __builtin_amdgcn_sched_barrier(0);                                         \
    __builtin_amdgcn_s_setprio(1);                                             \
    mmq(acc1, 4, A1C, B1C);                                                    \
    __builtin_amdgcn_s_setprio(0);                                             \
    __builtin_amdgcn_sched_barrier(0);                                         \
    __builtin_amdgcn_s_barrier();                                              \
  }

__global__ __launch_bounds__(512, 2)
void gemm_mlp(const unsigned short* __restrict__ A, int lda,
              const unsigned short* __restrict__ B0,
              const unsigned short* __restrict__ B1,
              const float* __restrict__ bias0, const float* __restrict__ bias1,
              unsigned short* __restrict__ out, int ldc, int K) {
  __shared__ alignas(16) unsigned short As[2][256 * 64];
  __shared__ alignas(16) unsigned short Bs0[2][128 * 64];
  __shared__ alignas(16) unsigned short Bs1[2][128 * 64];

  const int tid = threadIdx.x;
  const int l = tid & 63, w = tid >> 6;
  const int wr = w >> 2, wc = w & 3;
  const int lr = l & 15, lg = l >> 4;

  int m0, n0;
  xcd_map(128, m0, n0);
  const int NT = K >> 6;  // even (K=2048 -> 32)

  f32x4 acc0[8][2], acc1[8][2];
  const f32x4 z4 = {0.f, 0.f, 0.f, 0.f};
#pragma unroll
  for (int i = 0; i < 8; ++i)
#pragma unroll
    for (int j = 0; j < 2; ++j) { acc0[i][j] = z4; acc1[i][j] = z4; }

  // per-lane LDS read bases (byte addr, addrspace-3); kk folded into two bases
  const int s7 = lr & 7;
  const unsigned swz0 = (unsigned)((lg ^ s7) << 4);
  const unsigned swz1 = (unsigned)(((4 | lg) ^ s7) << 4);
  const unsigned rA = (unsigned)((wr * 128 + lr) * 128);
  const unsigned rB = (unsigned)((wc * 32 + lr) * 128);
  const unsigned aA0 = ldsoff(&As[0][0]) + rA + swz0;
  const unsigned aA1 = ldsoff(&As[0][0]) + rA + swz1;
  const unsigned bA0 = ldsoff(&Bs0[0][0]) + rB + swz0;
  const unsigned bA1 = ldsoff(&Bs0[0][0]) + rB + swz1;
  const unsigned cA0 = ldsoff(&Bs1[0][0]) + rB + swz0;
  const unsigned cA1 = ldsoff(&Bs1[0][0]) + rB + swz1;

  bf16x8 a0X[4][2], a1X[4][2], b0X[2][2], b1X[2][2];
  bf16x8 a0Y[4][2], a1Y[4][2], b0Y[2][2], b1Y[2][2];

  // prologue: tile0 (4 regions) then tile1 in steady-state order
  stage_half(A, lda, m0, 0, 0, As[0], tid);
  stage_half(A, lda, m0, 0, 1, As[0], tid);
  stage_half(B0, K, n0, 0, 0, Bs0[0], tid);
  stage_half(B1, K, n0, 0, 0, Bs1[0], tid);
  stage_half(B0, K, n0, 64, 0, Bs0[1], tid);
  stage_half(B1, K, n0, 64, 0, Bs1[1], tid);
  stage_half(A, lda, m0, 64, 0, As[1], tid);
  stage_half(A, lda, m0, 64, 1, As[1], tid);
  vmc<8>();
  __builtin_amdgcn_s_barrier();
  // pre-issue iter-0 P1 operands: a0(0), b0(0)
  RDA(a0X, aA0, aA1, 0);
  RDB(b0X, bA0, bA1, 0);

  for (int t = 0; t < NT; t += 2) {
    MLP_ITER(t, 0, a0X, b0X, b1X, a1X, a0Y, b0Y);
    MLP_ITER(t + 1, 1, a0Y, b0Y, b1Y, a1Y, a0X, b0X);
  }

  // epilogue: out bf16 = (acc0+bias0) * silu(acc1+bias1)
#pragma unroll
  for (int i = 0; i < 8; ++i) {
    int r0 = m0 + wr * 128 + i * 16 + lg * 4;
#pragma unroll
    for (int j = 0; j < 2; ++j) {
      int col = n0 + wc * 32 + j * 16 + lr;
      float bb0 = bias0[col];
      float bb1 = bias1[col];
#pragma unroll
      for (int q = 0; q < 4; ++q) {
        size_t off = (size_t)(r0 + q) * ldc + col;
        float v = acc0[i][j][q] + bb0;
        float gt = acc1[i][j][q] + bb1;
        out[off] = f2bf(v * (gt / (1.f + expf(-gt))));
      }
    }
  }
}

// ---------- flash attention: paired q-tiles, T14 reg-prefetch, exp2 softmax ----
__global__ __launch_bounds__(256, 3)
void attn_kernel(const unsigned short* __restrict__ qkv,
                 const unsigned short* __restrict__ vT,
                 unsigned short* __restrict__ ctx) {
  __shared__ unsigned short Ks[64 * 128];
  __shared__ unsigned short Vs[128 * 64];
  __shared__ unsigned short Ps[4][16 * 80];

  const int pid = blockIdx.x, bh = blockIdx.y;
  const int b = bh >> 4, h = bh & 15;
  const int tid = threadIdx.x, l = tid & 63, w = tid >> 6;
  const int lr = l & 15, lg = l >> 4;
  const float slope2 = exp2f(-0.5f * (float)(h + 1)) * 1.44269504f;
  const float SC2 = 0.0078125f * 1.44269504f;

  const int krow = tid >> 4, kcb = tid & 15;
  const int vrow = tid >> 3, vcb = tid & 7;
  const unsigned short* kbase = qkv + (size_t)(b * 2048 + krow) * 6144 + 2048 + h * 128 + kcb * 8;
  const unsigned short* vbase = vT + (size_t)(bh * 128 + vrow) * 2048 + vcb * 8;
  char* kdst = (char*)Ks + krow * 256 + ((kcb ^ (krow & 7)) << 4);
  char* vdst = (char*)Vs + vrow * 128 + ((vcb ^ (vrow & 7)) << 4);

  int4 kr[4], vr[4];
#pragma unroll
  for (int p = 0; p < 4; ++p) {
    kr[p] = *(const int4*)(kbase + (size_t)p * 16 * 6144);
    vr[p] = *(const int4*)(vbase + (size_t)p * 32 * 2048);
  }

  for (int tq = 0; tq < 2; ++tq) {
    const int qb = tq ? (31 - pid) : pid;
    const int q0 = qb * 64;
    bf16x8 aq[4];
    {
      const unsigned short* qp =
          qkv + (size_t)(b * 2048 + q0 + w * 16 + lr) * 6144 + h * 128 + lg * 8;
#pragma unroll
      for (int kk = 0; kk < 4; ++kk) aq[kk] = *(const bf16x8*)(qp + kk * 32);
    }
    const f32x4 z4 = {0.f, 0.f, 0.f, 0.f};
    f32x4 acc[8];
#pragma unroll
    for (int dt = 0; dt < 8; ++dt) acc[dt] = z4;
    float m_r[4] = {-INFINITY, -INFINITY, -INFINITY, -INFINITY};
    float l_r[4] = {0.f, 0.f, 0.f, 0.f};
    const int ibase = q0 + w * 16 + lg * 4;
    const int nc = qb + 1;

    for (int c = 0; c < nc; ++c) {
      const int kv0 = c * 64;
      __syncthreads();
#pragma unroll
      for (int p = 0; p < 4; ++p) {
        *(int4*)(kdst + p * 4096) = kr[p];
        *(int4*)(vdst + p * 4096) = vr[p];
      }
      __syncthreads();
      {
        int nxt = (c + 1 < nc) ? (c + 1) * 64 : (tq == 0 ? 0 : -1);
        if (nxt >= 0) {
#pragma unroll
          for (int p = 0; p < 4; ++p) {
            kr[p] = *(const int4*)(kbase + (size_t)nxt * 6144 + (size_t)p * 16 * 6144);
            vr[p] = *(const int4*)(vbase + nxt + (size_t)p * 32 * 2048);
          }
        }
      }

      f32x4 sc[4];
#pragma unroll
      for (int t = 0; t < 4; ++t) sc[t] = z4;
      __builtin_amdgcn_s_setprio(1);
#pragma unroll
      for (int t = 0; t < 4; ++t) {
#pragma unroll
        for (int kk = 0; kk < 4; ++kk) {
          int row = t * 16 + lr;
          int bo = (row * 256 + kk * 64 + lg * 16) ^ ((row & 7) << 4);
          bf16x8 bk = *(const bf16x8*)((const char*)Ks + bo);
          sc[t] = __builtin_amdgcn_mfma_f32_16x16x32_bf16(aq[kk], bk, sc[t], 0, 0, 0);
        }
      }
      __builtin_amdgcn_s_setprio(0);
      float cmax[4] = {-INFINITY, -INFINITY, -INFINITY, -INFINITY};
#pragma unroll
      for (int t = 0; t < 4; ++t)
#pragma unroll
        for (int q = 0; q < 4; ++q) {
          int j = kv0 + t * 16 + lr;
          int i = ibase + q;
          float s = sc[t][q] * SC2 + slope2 * (float)(j - i);
          if (j > i) s = -1e9f;
          sc[t][q] = s;
          cmax[q] = fmaxf(cmax[q], s);
        }
#pragma unroll
      for (int q = 0; q < 4; ++q) {
        float v = cmax[q];
        v = fmaxf(v, __shfl_xor(v, 1));
        v = fmaxf(v, __shfl_xor(v, 2));
        v = fmaxf(v, __shfl_xor(v, 4));
        v = fmaxf(v, __shfl_xor(v, 8));
        cmax[q] = v;
      }
      float alpha[4], rsum[4];
#pragma unroll
      for (int q = 0; q < 4; ++q) {
        float mn = fmaxf(m_r[q], cmax[q]);
        alpha[q] = exp2f(m_r[q] - mn);
        m_r[q] = mn;
        rsum[q] = 0.f;
      }
#pragma unroll
      for (int t = 0; t < 4; ++t)
#pragma unroll
        for (int q = 0; q < 4; ++q) {
          float p = exp2f(sc[t][q] - m_r[q]);
          rsum[q] += p;
          sc[t][q] = p;
        }
#pragma unroll
      for (int q = 0; q < 4; ++q) {
        float v = rsum[q];
        v += __shfl_xor(v, 1);
        v += __shfl_xor(v, 2);
        v += __shfl_xor(v, 4);
        v += __shfl_xor(v, 8);
        l_r[q] = l_r[q] * alpha[q] + v;
      }
#pragma unroll
      for (int dt = 0; dt < 8; ++dt)
#pragma unroll
        for (int q = 0; q < 4; ++q) acc[dt][q] *= alpha[q];
#pragma unroll
      for (int t = 0; t < 4; ++t)
#pragma unroll
        for (int q = 0; q < 4; ++q)
          Ps[w][(lg * 4 + q) * 80 + t * 16 + lr] = f2bf(sc[t][q]);
      __builtin_amdgcn_s_setprio(1);
#pragma unroll
      for (int kc = 0; kc < 2; ++kc) {
        bf16x8 ap = *(const bf16x8*)(&Ps[w][lr * 80 + kc * 32 + lg * 8]);
#pragma unroll
        for (int dt = 0; dt < 8; ++dt) {
          int row = dt * 16 + lr;
          int bo = (row * 128 + kc * 64 + lg * 16) ^ ((row & 7) << 4);
          bf16x8 bv = *(const bf16x8*)((const char*)Vs + bo);
          acc[dt] = __builtin_amdgcn_mfma_f32_16x16x32_bf16(ap, bv, acc[dt], 0, 0, 0);
        }
      }
      __builtin_amdgcn_s_setprio(0);
    }
#pragma unroll
    for (int q = 0; q < 4; ++q) {
      float inv = 1.f / l_r[q];
      int row = ibase + q;
#pragma unroll
      for (int dt = 0; dt < 8; ++dt)
        ctx[(size_t)(b * 2048 + row) * 2048 + h * 128 + dt * 16 + lr] =
            f2bf(acc[dt][q] * inv);
    }
  }
}

// ---------- launch ----------
extern "C" void kernel_launch(void* const* d_in, const int* in_sizes, int n_in,
                              void* d_out, int out_size, void* d_ws, size_t ws_size,
                              hipStream_t stream) {
  const float* hs   = (const float*)d_in[0];
  const float* ln1g = (const float*)d_in[3];
  const float* ln1b = (const float*)d_in[4];
  const float* wqkv = (const float*)d_in[5];
  const float* bqkv = (const float*)d_in[6];
  const float* wo   = (const float*)d_in[7];
  const float* bo   = (const float*)d_in[8];
  const float* ln2g = (const float*)d_in[9];
  const float* ln2b = (const float*)d_in[10];
  const float* wfc  = (const float*)d_in[11];
  const float* bfc  = (const float*)d_in[12];
  const float* wfc2 = (const float*)d_in[13];
  const float* bfc2 = (const float*)d_in[14];
  const float* wpj  = (const float*)d_in[15];
  const float* bpj  = (const float*)d_in[16];

  char* ws = (char*)d_ws;
  unsigned short* woT   = (unsigned short*)(ws + 0);          //  8 MB
  unsigned short* wfcT  = (unsigned short*)(ws + 8388608);    // 24 MB
  unsigned short* wfc2T = (unsigned short*)(ws + 33554432);   // 24 MB
  unsigned short* hbuf  = (unsigned short*)(ws + 58720256);   // 16 MB
  unsigned short* qkvb  = (unsigned short*)(ws + 75497472);   // 48 MB (later mlp_in)
  unsigned short* wqkvT = (unsigned short*)(ws + 125829120);  // 24 MB (later wpjT)
  unsigned short* vTb   = (unsigned short*)(ws + 150994944);  // 16 MB
  unsigned short* ctxb  = (unsigned short*)(ws + 167772160);  // 16 MB
  unsigned short* wpjT  = wqkvT;
  float* outf = (float*)d_out;

  dim3 blk(256), blk512(512);
  transpose_cast_f32<<<dim3(96, 32), blk, 0, stream>>>(wqkv, wqkvT, 2048, 6144);
  transpose_cast_f32<<<dim3(32, 32), blk, 0, stream>>>(wo, woT, 2048, 2048);
  transpose_cast_f32<<<dim3(96, 32), blk, 0, stream>>>(wfc, wfcT, 2048, 6144);
  transpose_cast_f32<<<dim3(96, 32), blk, 0, stream>>>(wfc2, wfc2T, 2048, 6144);
  ln_kernel<<<dim3(4096), blk, 0, stream>>>(hs, ln1g, ln1b, hbuf);
  // QKV: [4096,2048] x [6144,2048]^T -> [4096,6144] bf16
  gemm256<0><<<dim3(24, 16), blk512, 0, stream>>>(hbuf, 2048, wqkvT, bqkv, nullptr,
                                                  qkvb, 6144, 2048);
  transpose_v<<<dim3(32, 2, 32), blk, 0, stream>>>(qkvb, vTb);
  transpose_cast_f32<<<dim3(32, 96), blk, 0, stream>>>(wpj, wpjT, 6144, 2048);
  // attention (paired q-tiles)
  attn_kernel<<<dim3(16, 32), blk, 0, stream>>>(qkvb, vTb, ctxb);
  // O-proj + residual -> d_out f32  (grid 256 = full GPU)
  gemm_n128<1, false><<<dim3(16, 16), blk512, 0, stream>>>(
      ctxb, 2048, woT, nullptr, bo, nullptr, hs, d_out, 2048, 2048);
  ln_kernel<<<dim3(4096), blk, 0, stream>>>(outf, ln2g, ln2b, hbuf);
  // fused MLP gate/up: out = (h2@wfc + bfc) * silu(h2@wfc2 + bfc2)
  gemm_mlp<<<dim3(48, 16), blk512, 0, stream>>>(
      hbuf, 2048, wfcT, wfc2T, bfc, bfc2, qkvb, 6144, 2048);
  // proj + residual -> d_out
  gemm_n128<1, false><<<dim3(16, 16), blk512, 0, stream>>>(
      qkvb, 6144, wpjT, nullptr, bpj, nullptr, outf, d_out, 2048, 6144);
}

// Round 3
// 716.459 us; speedup vs baseline: 1.1169x; 1.0828x over previous
//
#include <hip/hip_runtime.h>
#include <hip/hip_bf16.h>
#include <math.h>

#define DI __device__ __forceinline__

typedef __bf16 bf16x8 __attribute__((ext_vector_type(8)));
typedef float f32x4 __attribute__((ext_vector_type(4)));
typedef short s16x8 __attribute__((ext_vector_type(8)));

// ---------- helpers ----------
DI unsigned short f2bf(float f) {
  unsigned int u = __builtin_bit_cast(unsigned int, f);
  unsigned int r = (u + 0x7fffu + ((u >> 16) & 1u)) >> 16;
  return (unsigned short)r;
}
DI float bf2f(unsigned short h) {
  unsigned int u = ((unsigned int)h) << 16;
  return __builtin_bit_cast(float, u);
}

DI void gload16(const void* g, void* l) {
  __builtin_amdgcn_global_load_lds(
      (const __attribute__((address_space(1))) void*)g,
      (__attribute__((address_space(3))) void*)l, 16, 0, 0);
}

DI unsigned ldsoff(const void* p) {
  return (unsigned)(size_t)(const __attribute__((address_space(3))) void*)p;
}

// asm ds_read_b128 with compile-time offset: compiler cannot sink/elide it, so
// prefetched fragments stay issued where we put them.
template <int OFF>
DI bf16x8 ds128(unsigned base) {
  bf16x8 r;
  asm volatile("ds_read_b128 %0, %1 offset:%2" : "=v"(r) : "v"(base), "i"(OFF));
  return r;
}
// counted waits + sched_barrier(0) (MFMA intrinsics can hoist past bare
// inline-asm waitcnt; the sched_barrier pins them below).
template <int N>
DI void lgkm() {
  asm volatile("s_waitcnt lgkmcnt(%0)" ::"i"(N));
  __builtin_amdgcn_sched_barrier(0);
}
template <int N>
DI void vmc() {
  asm volatile("s_waitcnt vmcnt(%0)" ::"i"(N));
  __builtin_amdgcn_sched_barrier(0);
}

// 2-D XCD rasterization for GEMMs: XCD grid 2(m) x 4(n); within an XCD,
// m-fastest so the ~32 co-resident blocks form an 8m x 4n rectangle.
DI void xcd_map(int BN, int& m0, int& n0) {
  const int nx = gridDim.x;
  int orig = blockIdx.y * nx + blockIdx.x;
  int xcd = orig & 7, k = orig >> 3;
  int xm = xcd >> 2, xn = xcd & 3;
  int nband = nx >> 2;
  m0 = (xm * 8 + (k & 7)) * 256;
  n0 = (xn * nband + (k >> 3)) * BN;
}

// ---------- transpose + fp32->bf16 cast: out[c][r] = bf16(in[r][c]) ----------
__global__ __launch_bounds__(256)
void transpose_cast_f32(const float* __restrict__ in, unsigned short* __restrict__ out,
                        int R, int C) {
  __shared__ unsigned int t[64 * 65];
  const int r0 = blockIdx.y * 64, c0 = blockIdx.x * 64;
  const int tid = threadIdx.x;
#pragma unroll
  for (int p = 0; p < 4; ++p) {
    int e = p * 1024 + tid * 4;
    int r = e >> 6, c = e & 63;
    float4 v = *(const float4*)(in + (size_t)(r0 + r) * C + c0 + c);
    t[r * 65 + c + 0] = f2bf(v.x);
    t[r * 65 + c + 1] = f2bf(v.y);
    t[r * 65 + c + 2] = f2bf(v.z);
    t[r * 65 + c + 3] = f2bf(v.w);
  }
  __syncthreads();
  const int oc = tid >> 2, ch = tid & 3;
  alignas(16) unsigned short vals[16];
#pragma unroll
  for (int j = 0; j < 16; ++j) vals[j] = (unsigned short)t[(ch * 16 + j) * 65 + oc];
  size_t ob = (size_t)(c0 + oc) * R + r0 + ch * 16;
  *(s16x8*)(out + ob) = *(const s16x8*)(vals);
  *(s16x8*)(out + ob + 8) = *(const s16x8*)(vals + 8);
}

// ---------- V transpose: qkv[b][s][4096+h*128+d] -> vT[bh][d][s] (bf16) ----------
__global__ __launch_bounds__(256)
void transpose_v(const unsigned short* __restrict__ qkv, unsigned short* __restrict__ vT) {
  __shared__ unsigned int t[64 * 65];
  const int s0 = blockIdx.x * 64, d0 = blockIdx.y * 64, bh = blockIdx.z;
  const int b = bh >> 4, h = bh & 15;
  const int tid = threadIdx.x;
#pragma unroll
  for (int p = 0; p < 2; ++p) {
    int id = p * 256 + tid;
    int r = id >> 3, c = (id & 7) * 8;
    s16x8 v = *(const s16x8*)(qkv + (size_t)(b * 2048 + s0 + r) * 6144 + 4096 + h * 128 + d0 + c);
#pragma unroll
    for (int j = 0; j < 8; ++j) t[r * 65 + c + j] = (unsigned short)((const unsigned short*)&v)[j];
  }
  __syncthreads();
  const int oc = tid >> 2, ch = tid & 3;
  alignas(16) unsigned short vals[16];
#pragma unroll
  for (int j = 0; j < 16; ++j) vals[j] = (unsigned short)t[(ch * 16 + j) * 65 + oc];
  size_t ob = (size_t)(bh * 128 + d0 + oc) * 2048 + s0 + ch * 16;
  *(s16x8*)(vT + ob) = *(const s16x8*)(vals);
  *(s16x8*)(vT + ob + 8) = *(const s16x8*)(vals + 8);
}

// ---------- LayerNorm fp32 -> bf16, row = 2048 ----------
__global__ __launch_bounds__(256)
void ln_kernel(const float* __restrict__ x, const float* __restrict__ g,
               const float* __restrict__ bi, unsigned short* __restrict__ y) {
  __shared__ float red[8];
  const int row = blockIdx.x, tid = threadIdx.x;
  const float* xp = x + (size_t)row * 2048 + tid * 8;
  float4 v0 = *(const float4*)xp;
  float4 v1 = *(const float4*)(xp + 4);
  float v[8] = {v0.x, v0.y, v0.z, v0.w, v1.x, v1.y, v1.z, v1.w};
  float s = 0.f;
#pragma unroll
  for (int j = 0; j < 8; ++j) s += v[j];
#pragma unroll
  for (int d = 1; d < 64; d <<= 1) s += __shfl_xor(s, d);
  if ((tid & 63) == 0) red[tid >> 6] = s;
  __syncthreads();
  float mean = (red[0] + red[1] + red[2] + red[3]) * (1.f / 2048.f);
  float dd[8], sq = 0.f;
#pragma unroll
  for (int j = 0; j < 8; ++j) { dd[j] = v[j] - mean; sq += dd[j] * dd[j]; }
#pragma unroll
  for (int d = 1; d < 64; d <<= 1) sq += __shfl_xor(sq, d);
  if ((tid & 63) == 0) red[4 + (tid >> 6)] = sq;
  __syncthreads();
  float var = (red[4] + red[5] + red[6] + red[7]) * (1.f / 2048.f);
  float rs = rsqrtf(var + 1e-5f);
  float4 g0 = *(const float4*)(g + tid * 8), g1 = *(const float4*)(g + tid * 8 + 4);
  float4 b0 = *(const float4*)(bi + tid * 8), b1 = *(const float4*)(bi + tid * 8 + 4);
  float gg[8] = {g0.x, g0.y, g0.z, g0.w, g1.x, g1.y, g1.z, g1.w};
  float bb[8] = {b0.x, b0.y, b0.z, b0.w, b1.x, b1.y, b1.z, b1.w};
  alignas(16) unsigned short o[8];
#pragma unroll
  for (int j = 0; j < 8; ++j) o[j] = f2bf(dd[j] * rs * gg[j] + bb[j]);
  *(s16x8*)(y + (size_t)row * 2048 + tid * 8) = *(const s16x8*)o;
}

// ---------- shared GEMM staging helpers ----------
DI void stage_half(const unsigned short* __restrict__ G, int ld, int rbase, int kt,
                   int h, unsigned short* dst, int tid) {
#pragma unroll
  for (int i = 0; i < 2; ++i) {
    int id = i * 512 + tid;
    int rl = id >> 3, sl = id & 7;
    int ss = sl ^ (rl & 7);
    gload16(G + (size_t)(rbase + h * 128 + rl) * ld + kt + ss * 8,
            (char*)dst + h * 16384 + id * 16);
  }
}

DI bf16x8 ldsrd(const unsigned short* buf, int row, int ks) {
  return *(const bf16x8*)((const char*)buf + row * 128 + ((ks ^ (row & 7)) << 4));
}

// ---------- 256x256 GEMM, 4 clusters/K-tile, read-hoisted schedule ----------
// MODE 0: out bf16 = acc + bias ; MODE 1: out f32 = acc + bias + res
template <int MODE>
__global__ __launch_bounds__(512, 2)
void gemm256(const unsigned short* __restrict__ A, int lda,
             const unsigned short* __restrict__ B,
             const float* __restrict__ bias,
             const void* __restrict__ resg,
             void* __restrict__ out, int ldc, int K) {
  __shared__ alignas(16) unsigned short As[2][256 * 64];
  __shared__ alignas(16) unsigned short Bs[2][256 * 64];

  const int tid = threadIdx.x;
  const int l = tid & 63, w = tid >> 6;
  const int wr = w >> 2, wc = w & 3;
  const int lr = l & 15, lg = l >> 4;

  int m0, n0;
  xcd_map(256, m0, n0);

  const int NT = K >> 6;

  f32x4 acc[8][4];
  const f32x4 z4 = {0.f, 0.f, 0.f, 0.f};
#pragma unroll
  for (int i = 0; i < 8; ++i)
#pragma unroll
    for (int j = 0; j < 4; ++j) acc[i][j] = z4;

  stage_half(A, lda, m0, 0, 0, As[0], tid);
  stage_half(A, lda, m0, 0, 1, As[0], tid);
  stage_half(B, K, n0, 0, 0, Bs[0], tid);
  stage_half(B, K, n0, 0, 1, Bs[0], tid);
  if (NT > 1) {
    stage_half(B, K, n0, 64, 0, Bs[1], tid);
    stage_half(B, K, n0, 64, 1, Bs[1], tid);
    stage_half(A, lda, m0, 64, 0, As[1], tid);
    asm volatile("s_waitcnt vmcnt(6)" ::: "memory");
  } else {
    asm volatile("s_waitcnt vmcnt(0)" ::: "memory");
  }
  __builtin_amdgcn_s_barrier();

  for (int t = 0; t < NT; ++t) {
    const int cur = t & 1;
    const unsigned short* Ac = As[cur];
    const unsigned short* Bc = Bs[cur];
    bf16x8 a0[4][2], a1[4][2], bfr[4][2];

    // ---- c1: issue a0(8)+b0123(8); stage A-h1(t+1)->nxt; Q1 = a0 x b01 ----
#pragma unroll
    for (int i = 0; i < 4; ++i)
#pragma unroll
      for (int kk = 0; kk < 2; ++kk)
        a0[i][kk] = ldsrd(Ac, wr * 128 + i * 16 + lr, kk * 4 + lg);
#pragma unroll
    for (int j = 0; j < 2; ++j)
#pragma unroll
      for (int kk = 0; kk < 2; ++kk)
        bfr[j][kk] = ldsrd(Bc, wc * 64 + j * 16 + lr, kk * 4 + lg);
    if (t + 1 < NT) stage_half(A, lda, m0, (t + 1) * 64, 1, As[cur ^ 1], tid);
#pragma unroll
    for (int j = 2; j < 4; ++j)
#pragma unroll
      for (int kk = 0; kk < 2; ++kk)
        bfr[j][kk] = ldsrd(Bc, wc * 64 + j * 16 + lr, kk * 4 + lg);
    __builtin_amdgcn_s_setprio(1);
#pragma unroll
    for (int i = 0; i < 4; ++i)
#pragma unroll
      for (int j = 0; j < 2; ++j)
#pragma unroll
        for (int kk = 0; kk < 2; ++kk)
          acc[i][j] = __builtin_amdgcn_mfma_f32_16x16x32_bf16(a0[i][kk], bfr[j][kk], acc[i][j], 0, 0, 0);
    __builtin_amdgcn_s_setprio(0);
    __builtin_amdgcn_s_barrier();

    // ---- c2: Q2 = a0 x b23; a1 issued under the MFMAs ----
    __builtin_amdgcn_s_setprio(1);
#pragma unroll
    for (int i = 0; i < 4; ++i) {
#pragma unroll
      for (int j = 2; j < 4; ++j)
#pragma unroll
        for (int kk = 0; kk < 2; ++kk)
          acc[i][j] = __builtin_amdgcn_mfma_f32_16x16x32_bf16(a0[i][kk], bfr[j][kk], acc[i][j], 0, 0, 0);
#pragma unroll
      for (int kk = 0; kk < 2; ++kk)
        a1[i][kk] = ldsrd(Ac, wr * 128 + 64 + i * 16 + lr, kk * 4 + lg);
    }
    __builtin_amdgcn_s_setprio(0);
    __builtin_amdgcn_s_barrier();

    // ---- c3: stage B-h0(t+2)->cur; Q3 ----
    if (t + 2 < NT) stage_half(B, K, n0, (t + 2) * 64, 0, Bs[cur], tid);
    __builtin_amdgcn_s_setprio(1);
#pragma unroll
    for (int i = 0; i < 4; ++i)
#pragma unroll
      for (int j = 0; j < 2; ++j)
#pragma unroll
        for (int kk = 0; kk < 2; ++kk)
          acc[i + 4][j] = __builtin_amdgcn_mfma_f32_16x16x32_bf16(a1[i][kk], bfr[j][kk], acc[i + 4][j], 0, 0, 0);
    __builtin_amdgcn_s_setprio(0);
    __builtin_amdgcn_s_barrier();

    // ---- c4: stage B-h1(t+2)+A-h0(t+2)->cur; Q4 ----
    if (t + 2 < NT) {
      stage_half(B, K, n0, (t + 2) * 64, 1, Bs[cur], tid);
      stage_half(A, lda, m0, (t + 2) * 64, 0, As[cur], tid);
    }
    __builtin_amdgcn_s_setprio(1);
#pragma unroll
    for (int i = 0; i < 4; ++i)
#pragma unroll
      for (int j = 2; j < 4; ++j)
#pragma unroll
        for (int kk = 0; kk < 2; ++kk)
          acc[i + 4][j] = __builtin_amdgcn_mfma_f32_16x16x32_bf16(a1[i][kk], bfr[j][kk], acc[i + 4][j], 0, 0, 0);
    __builtin_amdgcn_s_setprio(0);
    if (t + 2 < NT) {
      asm volatile("s_waitcnt vmcnt(6)" ::: "memory");
    } else {
      asm volatile("s_waitcnt vmcnt(0)" ::: "memory");
    }
    __builtin_amdgcn_s_barrier();
  }

#pragma unroll
  for (int i = 0; i < 8; ++i) {
    int r0 = m0 + wr * 128 + i * 16 + lg * 4;
#pragma unroll
    for (int j = 0; j < 4; ++j) {
      int col = n0 + wc * 64 + j * 16 + lr;
      float bb = bias[col];
#pragma unroll
      for (int q = 0; q < 4; ++q) {
        size_t off = (size_t)(r0 + q) * ldc + col;
        float v = acc[i][j][q] + bb;
        if (MODE == 0) {
          ((unsigned short*)out)[off] = f2bf(v);
        } else {
          ((float*)out)[off] = v + ((const float*)resg)[off];
        }
      }
    }
  }
}

// ---------- 256x128 GEMM, single-B (2-cluster) ----------
// MODE 1: out f32 = acc0 + bias0 + res
template <int MODE, bool DUAL>
__global__ __launch_bounds__(512, 2)
void gemm_n128(const unsigned short* __restrict__ A, int lda,
               const unsigned short* __restrict__ B0,
               const unsigned short* __restrict__ B1,
               const float* __restrict__ bias0, const float* __restrict__ bias1,
               const void* __restrict__ resg,
               void* __restrict__ out, int ldc, int K) {
  __shared__ alignas(16) unsigned short As[2][256 * 64];
  __shared__ alignas(16) unsigned short Bs0[2][128 * 64];

  const int tid = threadIdx.x;
  const int l = tid & 63, w = tid >> 6;
  const int wr = w >> 2, wc = w & 3;
  const int lr = l & 15, lg = l >> 4;

  int m0, n0;
  xcd_map(128, m0, n0);

  const int NT = K >> 6;

  f32x4 acc0[8][2];
  const f32x4 z4 = {0.f, 0.f, 0.f, 0.f};
#pragma unroll
  for (int i = 0; i < 8; ++i)
#pragma unroll
    for (int j = 0; j < 2; ++j) acc0[i][j] = z4;

  // prologue
  stage_half(A, lda, m0, 0, 0, As[0], tid);
  stage_half(A, lda, m0, 0, 1, As[0], tid);
  stage_half(B0, K, n0, 0, 0, Bs0[0], tid);
  if (NT > 1) {
    stage_half(B0, K, n0, 64, 0, Bs0[1], tid);
    stage_half(A, lda, m0, 64, 0, As[1], tid);
    asm volatile("s_waitcnt vmcnt(4)" ::: "memory");
  } else {
    asm volatile("s_waitcnt vmcnt(0)" ::: "memory");
  }
  __builtin_amdgcn_s_barrier();

  for (int t = 0; t < NT; ++t) {
    const int cur = t & 1;
    const unsigned short* Ac = As[cur];
    const unsigned short* Bc0 = Bs0[cur];
    bf16x8 a0[4][2], a1[4][2], b0f[2][2];

    // ---- c1: issue a0(8)+b0(4); stage A-h1(t+1)->nxt; MFMA + a1 issue ----
#pragma unroll
    for (int i = 0; i < 4; ++i)
#pragma unroll
      for (int kk = 0; kk < 2; ++kk)
        a0[i][kk] = ldsrd(Ac, wr * 128 + i * 16 + lr, kk * 4 + lg);
#pragma unroll
    for (int j = 0; j < 2; ++j)
#pragma unroll
      for (int kk = 0; kk < 2; ++kk)
        b0f[j][kk] = ldsrd(Bc0, wc * 32 + j * 16 + lr, kk * 4 + lg);
    if (t + 1 < NT) stage_half(A, lda, m0, (t + 1) * 64, 1, As[cur ^ 1], tid);

    __builtin_amdgcn_s_setprio(1);
#pragma unroll
    for (int i = 0; i < 4; ++i) {
#pragma unroll
      for (int j = 0; j < 2; ++j)
#pragma unroll
        for (int kk = 0; kk < 2; ++kk)
          acc0[i][j] = __builtin_amdgcn_mfma_f32_16x16x32_bf16(a0[i][kk], b0f[j][kk], acc0[i][j], 0, 0, 0);
#pragma unroll
      for (int kk = 0; kk < 2; ++kk)
        a1[i][kk] = ldsrd(Ac, wr * 128 + 64 + i * 16 + lr, kk * 4 + lg);
    }
    __builtin_amdgcn_s_setprio(0);
    __builtin_amdgcn_s_barrier();

    // ---- c2: stage B0(t+2)->cur; drain a1; stage A-h0(t+2)->cur; MFMA ----
    if (t + 2 < NT) stage_half(B0, K, n0, (t + 2) * 64, 0, Bs0[cur], tid);
    asm volatile("s_waitcnt lgkmcnt(0)" ::: "memory");
    if (t + 2 < NT) stage_half(A, lda, m0, (t + 2) * 64, 0, As[cur], tid);
    __builtin_amdgcn_s_setprio(1);
#pragma unroll
    for (int i = 0; i < 4; ++i)
#pragma unroll
      for (int j = 0; j < 2; ++j)
#pragma unroll
        for (int kk = 0; kk < 2; ++kk)
          acc0[i + 4][j] = __builtin_amdgcn_mfma_f32_16x16x32_bf16(a1[i][kk], b0f[j][kk], acc0[i + 4][j], 0, 0, 0);
    __builtin_amdgcn_s_setprio(0);
    if (t + 2 < NT) asm volatile("s_waitcnt vmcnt(4)" ::: "memory");
    else            asm volatile("s_waitcnt vmcnt(0)" ::: "memory");
    __builtin_amdgcn_s_barrier();
  }

  // epilogue
#pragma unroll
  for (int i = 0; i < 8; ++i) {
    int r0 = m0 + wr * 128 + i * 16 + lg * 4;
#pragma unroll
    for (int j = 0; j < 2; ++j) {
      int col = n0 + wc * 32 + j * 16 + lr;
      float bb0 = bias0[col];
#pragma unroll
      for (int q = 0; q < 4; ++q) {
        size_t off = (size_t)(r0 + q) * ldc + col;
        float v = acc0[i][j][q] + bb0;
        ((float*)out)[off] = v + ((const float*)resg)[off];
      }
    }
  }
}

// ---------- MLP dual GEMM: 256x128, counted-wait asm-pipelined 4-phase -------
DI void mmq(f32x4 (&acc)[8][2], int io, const bf16x8 (&af)[4][2], const bf16x8 (&bf)[2][2]) {
#pragma unroll
  for (int kk = 0; kk < 2; ++kk)
#pragma unroll
    for (int i = 0; i < 4; ++i)
#pragma unroll
      for (int j = 0; j < 2; ++j)
        acc[io + i][j] = __builtin_amdgcn_mfma_f32_16x16x32_bf16(af[i][kk], bf[j][kk], acc[io + i][j], 0, 0, 0);
}

#define RDA(dst, B0_, B1_, OFS)                                        \
  dst[0][0] = ds128<(OFS) + 0>(B0_);    dst[0][1] = ds128<(OFS) + 0>(B1_);    \
  dst[1][0] = ds128<(OFS) + 2048>(B0_); dst[1][1] = ds128<(OFS) + 2048>(B1_); \
  dst[2][0] = ds128<(OFS) + 4096>(B0_); dst[2][1] = ds128<(OFS) + 4096>(B1_); \
  dst[3][0] = ds128<(OFS) + 6144>(B0_); dst[3][1] = ds128<(OFS) + 6144>(B1_);

#define RDB(dst, B0_, B1_, OFS)                                        \
  dst[0][0] = ds128<(OFS) + 0>(B0_);    dst[0][1] = ds128<(OFS) + 0>(B1_);    \
  dst[1][0] = ds128<(OFS) + 2048>(B0_); dst[1][1] = ds128<(OFS) + 2048>(B1_);

#define MLP_ITER(t, CUR, A0C, B0C, B1C, A1C, A0N, B0N)                         \
  {                                                                            \
    /* P1: issue b1(t); wait a0(t),b0(t); Q1 = a0 x b0 -> acc0 lo */           \
    RDB(B1C, cA0, cA1, (CUR) * 16384);                                         \
    lgkm<4>();                                                                 \
    __builtin_amdgcn_s_setprio(1);                                             \
    mmq(acc0, 0, A0C, B0C);                                                    \
    __builtin_amdgcn_s_setprio(0);                                             \
    __builtin_amdgcn_sched_barrier(0);                                         \
    __builtin_amdgcn_s_barrier();                                              \
    /* P2: stage B0(t+2); issue a1(t); wait b1(t); Q2 = a0 x b1 -> acc1 lo */  \
    if ((t) + 2 < NT) stage_half(B0, K, n0, ((t) + 2) * 64, 0, Bs0[CUR], tid); \
    RDA(A1C, aA0, aA1, (CUR) * 32768 + 8192);                                  \
    lgkm<8>();                                                                 \
    __builtin_amdgcn_s_setprio(1);                                             \
    mmq(acc1, 0, A0C, B1C);                                                    \
    __builtin_amdgcn_s_setprio(0);                                             \
    if ((t) + 2 < NT) { vmc<2>(); } else { vmc<0>(); }                         \
    __builtin_amdgcn_s_barrier();                                              \
    /* P3: stage B1(t+2); issue a0(t+1); wait a1(t); Q3 = a1 x b0 -> acc0 hi */\
    if ((t) + 2 < NT) stage_half(B1, K, n0, ((t) + 2) * 64, 0, Bs1[CUR], tid); \
    RDA(A0N, aA0, aA1, ((CUR) ^ 1) * 32768);                                   \
    lgkm<8>();                                                                 \
    __builtin_amdgcn_s_setprio(1);                                             \
    mmq(acc0, 4, A1C, B0C);                                                    \
    __builtin_amdgcn_s_setprio(0);                                             \
    __builtin_amdgcn_sched_barrier(0);                                         \
    __builtin_amdgcn_s_barrier();                                              \
    /* P4: stage A(t+2) both halves; issue b0(t+1); Q4 = a1 x b1 -> acc1 hi */ \
    if ((t) + 2 < NT) {                                                        \
      stage_half(A, lda, m0, ((t) + 2) * 64, 0, As[CUR], tid);                 \
      stage_half(A, lda, m0, ((t) + 2) * 64, 1, As[CUR], tid);                 \
    }                                                                          \
    RDB(B0N, bA0, bA1, ((CUR) ^ 1) * 16384);                                   \
    __builtin_amdgcn_sched_barrier(0);                                         \
    __builtin_amdgcn_s_setprio(1);                                             \
    mmq(acc1, 4, A1C, B1C);                                                    \
    __builtin_amdgcn_s_setprio(0);                                             \
    __builtin_amdgcn_sched_barrier(0);                                         \
    __builtin_amdgcn_s_barrier();                                              \
  }

__global__ __launch_bounds__(512, 2)
void gemm_mlp(const unsigned short* __restrict__ A, int lda,
              const unsigned short* __restrict__ B0,
              const unsigned short* __restrict__ B1,
              const float* __restrict__ bias0, const float* __restrict__ bias1,
              unsigned short* __restrict__ out, int ldc, int K) {
  __shared__ alignas(16) unsigned short As[2][256 * 64];
  __shared__ alignas(16) unsigned short Bs0[2][128 * 64];
  __shared__ alignas(16) unsigned short Bs1[2][128 * 64];

  const int tid = threadIdx.x;
  const int l = tid & 63, w = tid >> 6;
  const int wr = w >> 2, wc = w & 3;
  const int lr = l & 15, lg = l >> 4;

  int m0, n0;
  xcd_map(128, m0, n0);
  const int NT = K >> 6;  // even (K=2048 -> 32)

  f32x4 acc0[8][2], acc1[8][2];
  const f32x4 z4 = {0.f, 0.f, 0.f, 0.f};
#pragma unroll
  for (int i = 0; i < 8; ++i)
#pragma unroll
    for (int j = 0; j < 2; ++j) { acc0[i][j] = z4; acc1[i][j] = z4; }

  const int s7 = lr & 7;
  const unsigned swz0 = (unsigned)((lg ^ s7) << 4);
  const unsigned swz1 = (unsigned)(((4 | lg) ^ s7) << 4);
  const unsigned rA = (unsigned)((wr * 128 + lr) * 128);
  const unsigned rB = (unsigned)((wc * 32 + lr) * 128);
  const unsigned aA0 = ldsoff(&As[0][0]) + rA + swz0;
  const unsigned aA1 = ldsoff(&As[0][0]) + rA + swz1;
  const unsigned bA0 = ldsoff(&Bs0[0][0]) + rB + swz0;
  const unsigned bA1 = ldsoff(&Bs0[0][0]) + rB + swz1;
  const unsigned cA0 = ldsoff(&Bs1[0][0]) + rB + swz0;
  const unsigned cA1 = ldsoff(&Bs1[0][0]) + rB + swz1;

  bf16x8 a0X[4][2], a1X[4][2], b0X[2][2], b1X[2][2];
  bf16x8 a0Y[4][2], a1Y[4][2], b0Y[2][2], b1Y[2][2];

  stage_half(A, lda, m0, 0, 0, As[0], tid);
  stage_half(A, lda, m0, 0, 1, As[0], tid);
  stage_half(B0, K, n0, 0, 0, Bs0[0], tid);
  stage_half(B1, K, n0, 0, 0, Bs1[0], tid);
  stage_half(B0, K, n0, 64, 0, Bs0[1], tid);
  stage_half(B1, K, n0, 64, 0, Bs1[1], tid);
  stage_half(A, lda, m0, 64, 0, As[1], tid);
  stage_half(A, lda, m0, 64, 1, As[1], tid);
  vmc<8>();
  __builtin_amdgcn_s_barrier();
  RDA(a0X, aA0, aA1, 0);
  RDB(b0X, bA0, bA1, 0);

  for (int t = 0; t < NT; t += 2) {
    MLP_ITER(t, 0, a0X, b0X, b1X, a1X, a0Y, b0Y);
    MLP_ITER(t + 1, 1, a0Y, b0Y, b1Y, a1Y, a0X, b0X);
  }

  // epilogue: out bf16 = (acc0+bias0) * silu(acc1+bias1)
#pragma unroll
  for (int i = 0; i < 8; ++i) {
    int r0 = m0 + wr * 128 + i * 16 + lg * 4;
#pragma unroll
    for (int j = 0; j < 2; ++j) {
      int col = n0 + wc * 32 + j * 16 + lr;
      float bb0 = bias0[col];
      float bb1 = bias1[col];
#pragma unroll
      for (int q = 0; q < 4; ++q) {
        size_t off = (size_t)(r0 + q) * ldc + col;
        float v = acc0[i][j][q] + bb0;
        float gt = acc1[i][j][q] + bb1;
        out[off] = f2bf(v * (gt / (1.f + expf(-gt))));
      }
    }
  }
}

// ---------- flash attention: paired q-tiles, XCD-local bh, coalesced out ----
// Grid is 1-D (512). Mapping confines each (b,h)'s 16 pid-blocks to ONE XCD
// (assuming round-robin linear-id -> XCD): per-XCD L2 then serves K/V to all
// 16 siblings (4 bh x 1MB = 4MB = L2). Epilogue stages each wave's 16x128
// output tile in a wave-private LDS buffer and stores coalesced 64B sectors
// (the scalar 2B stores were costing ~30x write amplification).
__global__ __launch_bounds__(256, 2)
void attn_kernel(const unsigned short* __restrict__ qkv,
                 const unsigned short* __restrict__ vT,
                 unsigned short* __restrict__ ctx) {
  __shared__ unsigned short Ks[64 * 128];
  __shared__ unsigned short Vs[128 * 64];
  __shared__ unsigned short Ps[4][16 * 80];
  __shared__ unsigned short Ob[4][16 * 136];

  const int g = blockIdx.x;
  const int xcd = g & 7, slot = g >> 3;
  const int bh = xcd * 4 + (slot & 3);
  const int pid = slot >> 2;
  const int b = bh >> 4, h = bh & 15;
  const int tid = threadIdx.x, l = tid & 63, w = tid >> 6;
  const int lr = l & 15, lg = l >> 4;
  const float slope2 = exp2f(-0.5f * (float)(h + 1)) * 1.44269504f;
  const float SC2 = 0.0078125f * 1.44269504f;

  const int krow = tid >> 4, kcb = tid & 15;
  const int vrow = tid >> 3, vcb = tid & 7;
  const unsigned short* kbase = qkv + (size_t)(b * 2048 + krow) * 6144 + 2048 + h * 128 + kcb * 8;
  const unsigned short* vbase = vT + (size_t)(bh * 128 + vrow) * 2048 + vcb * 8;
  char* kdst = (char*)Ks + krow * 256 + ((kcb ^ (krow & 7)) << 4);
  char* vdst = (char*)Vs + vrow * 128 + ((vcb ^ (vrow & 7)) << 4);

  int4 kr[4], vr[4];
#pragma unroll
  for (int p = 0; p < 4; ++p) {
    kr[p] = *(const int4*)(kbase + (size_t)p * 16 * 6144);
    vr[p] = *(const int4*)(vbase + (size_t)p * 32 * 2048);
  }

  for (int tq = 0; tq < 2; ++tq) {
    const int qb = tq ? (31 - pid) : pid;
    const int q0 = qb * 64;
    bf16x8 aq[4];
    {
      const unsigned short* qp =
          qkv + (size_t)(b * 2048 + q0 + w * 16 + lr) * 6144 + h * 128 + lg * 8;
#pragma unroll
      for (int kk = 0; kk < 4; ++kk) aq[kk] = *(const bf16x8*)(qp + kk * 32);
    }
    const f32x4 z4 = {0.f, 0.f, 0.f, 0.f};
    f32x4 acc[8];
#pragma unroll
    for (int dt = 0; dt < 8; ++dt) acc[dt] = z4;
    float m_r[4] = {-INFINITY, -INFINITY, -INFINITY, -INFINITY};
    float l_r[4] = {0.f, 0.f, 0.f, 0.f};
    const int ibase = q0 + w * 16 + lg * 4;
    const int nc = qb + 1;

    for (int c = 0; c < nc; ++c) {
      const int kv0 = c * 64;
      __syncthreads();
#pragma unroll
      for (int p = 0; p < 4; ++p) {
        *(int4*)(kdst + p * 4096) = kr[p];
        *(int4*)(vdst + p * 4096) = vr[p];
      }
      __syncthreads();
      {
        int nxt = (c + 1 < nc) ? (c + 1) * 64 : (tq == 0 ? 0 : -1);
        if (nxt >= 0) {
#pragma unroll
          for (int p = 0; p < 4; ++p) {
            kr[p] = *(const int4*)(kbase + (size_t)nxt * 6144 + (size_t)p * 16 * 6144);
            vr[p] = *(const int4*)(vbase + nxt + (size_t)p * 32 * 2048);
          }
        }
      }

      f32x4 sc[4];
#pragma unroll
      for (int t = 0; t < 4; ++t) sc[t] = z4;
      __builtin_amdgcn_s_setprio(1);
#pragma unroll
      for (int t = 0; t < 4; ++t) {
#pragma unroll
        for (int kk = 0; kk < 4; ++kk) {
          int row = t * 16 + lr;
          int bo = (row * 256 + kk * 64 + lg * 16) ^ ((row & 7) << 4);
          bf16x8 bk = *(const bf16x8*)((const char*)Ks + bo);
          sc[t] = __builtin_amdgcn_mfma_f32_16x16x32_bf16(aq[kk], bk, sc[t], 0, 0, 0);
        }
      }
      __builtin_amdgcn_s_setprio(0);
      float cmax[4] = {-INFINITY, -INFINITY, -INFINITY, -INFINITY};
#pragma unroll
      for (int t = 0; t < 4; ++t)
#pragma unroll
        for (int q = 0; q < 4; ++q) {
          int j = kv0 + t * 16 + lr;
          int i = ibase + q;
          float s = sc[t][q] * SC2 + slope2 * (float)(j - i);
          if (j > i) s = -1e9f;
          sc[t][q] = s;
          cmax[q] = fmaxf(cmax[q], s);
        }
#pragma unroll
      for (int q = 0; q < 4; ++q) {
        float v = cmax[q];
        v = fmaxf(v, __shfl_xor(v, 1));
        v = fmaxf(v, __shfl_xor(v, 2));
        v = fmaxf(v, __shfl_xor(v, 4));
        v = fmaxf(v, __shfl_xor(v, 8));
        cmax[q] = v;
      }
      float alpha[4], rsum[4];
#pragma unroll
      for (int q = 0; q < 4; ++q) {
        float mn = fmaxf(m_r[q], cmax[q]);
        alpha[q] = exp2f(m_r[q] - mn);
        m_r[q] = mn;
        rsum[q] = 0.f;
      }
#pragma unroll
      for (int t = 0; t < 4; ++t)
#pragma unroll
        for (int q = 0; q < 4; ++q) {
          float p = exp2f(sc[t][q] - m_r[q]);
          rsum[q] += p;
          sc[t][q] = p;
        }
#pragma unroll
      for (int q = 0; q < 4; ++q) {
        float v = rsum[q];
        v += __shfl_xor(v, 1);
        v += __shfl_xor(v, 2);
        v += __shfl_xor(v, 4);
        v += __shfl_xor(v, 8);
        l_r[q] = l_r[q] * alpha[q] + v;
      }
#pragma unroll
      for (int dt = 0; dt < 8; ++dt)
#pragma unroll
        for (int q = 0; q < 4; ++q) acc[dt][q] *= alpha[q];
#pragma unroll
      for (int t = 0; t < 4; ++t)
#pragma unroll
        for (int q = 0; q < 4; ++q)
          Ps[w][(lg * 4 + q) * 80 + t * 16 + lr] = f2bf(sc[t][q]);
      __builtin_amdgcn_s_setprio(1);
#pragma unroll
      for (int kc = 0; kc < 2; ++kc) {
        bf16x8 ap = *(const bf16x8*)(&Ps[w][lr * 80 + kc * 32 + lg * 8]);
#pragma unroll
        for (int dt = 0; dt < 8; ++dt) {
          int row = dt * 16 + lr;
          int bo = (row * 128 + kc * 64 + lg * 16) ^ ((row & 7) << 4);
          bf16x8 bv = *(const bf16x8*)((const char*)Vs + bo);
          acc[dt] = __builtin_amdgcn_mfma_f32_16x16x32_bf16(ap, bv, acc[dt], 0, 0, 0);
        }
      }
      __builtin_amdgcn_s_setprio(0);
    }

    // ---- coalesced epilogue: wave-private LDS transpose, 64B-sector stores --
    unsigned short* Kw = &Ob[w][0];
#pragma unroll
    for (int q = 0; q < 4; ++q) {
      float inv = 1.f / l_r[q];
      int rl = lg * 4 + q;
#pragma unroll
      for (int dt = 0; dt < 8; ++dt)
        Kw[rl * 136 + dt * 16 + lr] = f2bf(acc[dt][q] * inv);
    }
    const int rr = l >> 2, c4 = l & 3;
    const unsigned short* srow = Kw + rr * 136 + c4 * 8;
    size_t gb = (size_t)(b * 2048 + q0 + w * 16 + rr) * 2048 + h * 128 + c4 * 8;
#pragma unroll
    for (int k = 0; k < 4; ++k)
      *(s16x8*)(ctx + gb + k * 32) = *(const s16x8*)(srow + k * 32);
  }
}

// ---------- launch ----------
extern "C" void kernel_launch(void* const* d_in, const int* in_sizes, int n_in,
                              void* d_out, int out_size, void* d_ws, size_t ws_size,
                              hipStream_t stream) {
  const float* hs   = (const float*)d_in[0];
  const float* ln1g = (const float*)d_in[3];
  const float* ln1b = (const float*)d_in[4];
  const float* wqkv = (const float*)d_in[5];
  const float* bqkv = (const float*)d_in[6];
  const float* wo   = (const float*)d_in[7];
  const float* bo   = (const float*)d_in[8];
  const float* ln2g = (const float*)d_in[9];
  const float* ln2b = (const float*)d_in[10];
  const float* wfc  = (const float*)d_in[11];
  const float* bfc  = (const float*)d_in[12];
  const float* wfc2 = (const float*)d_in[13];
  const float* bfc2 = (const float*)d_in[14];
  const float* wpj  = (const float*)d_in[15];
  const float* bpj  = (const float*)d_in[16];

  char* ws = (char*)d_ws;
  unsigned short* woT   = (unsigned short*)(ws + 0);          //  8 MB
  unsigned short* wfcT  = (unsigned short*)(ws + 8388608);    // 24 MB
  unsigned short* wfc2T = (unsigned short*)(ws + 33554432);   // 24 MB
  unsigned short* hbuf  = (unsigned short*)(ws + 58720256);   // 16 MB
  unsigned short* qkvb  = (unsigned short*)(ws + 75497472);   // 48 MB (later mlp_in)
  unsigned short* wqkvT = (unsigned short*)(ws + 125829120);  // 24 MB (later wpjT)
  unsigned short* vTb   = (unsigned short*)(ws + 150994944);  // 16 MB
  unsigned short* ctxb  = (unsigned short*)(ws + 167772160);  // 16 MB
  unsigned short* wpjT  = wqkvT;
  float* outf = (float*)d_out;

  dim3 blk(256), blk512(512);
  transpose_cast_f32<<<dim3(96, 32), blk, 0, stream>>>(wqkv, wqkvT, 2048, 6144);
  transpose_cast_f32<<<dim3(32, 32), blk, 0, stream>>>(wo, woT, 2048, 2048);
  transpose_cast_f32<<<dim3(96, 32), blk, 0, stream>>>(wfc, wfcT, 2048, 6144);
  transpose_cast_f32<<<dim3(96, 32), blk, 0, stream>>>(wfc2, wfc2T, 2048, 6144);
  ln_kernel<<<dim3(4096), blk, 0, stream>>>(hs, ln1g, ln1b, hbuf);
  // QKV: [4096,2048] x [6144,2048]^T -> [4096,6144] bf16
  gemm256<0><<<dim3(24, 16), blk512, 0, stream>>>(hbuf, 2048, wqkvT, bqkv, nullptr,
                                                  qkvb, 6144, 2048);
  transpose_v<<<dim3(32, 2, 32), blk, 0, stream>>>(qkvb, vTb);
  transpose_cast_f32<<<dim3(32, 96), blk, 0, stream>>>(wpj, wpjT, 6144, 2048);
  // attention (paired q-tiles, XCD-local bh mapping)
  attn_kernel<<<dim3(512), blk, 0, stream>>>(qkvb, vTb, ctxb);
  // O-proj + residual -> d_out f32  (grid 256 = full GPU)
  gemm_n128<1, false><<<dim3(16, 16), blk512, 0, stream>>>(
      ctxb, 2048, woT, nullptr, bo, nullptr, hs, d_out, 2048, 2048);
  ln_kernel<<<dim3(4096), blk, 0, stream>>>(outf, ln2g, ln2b, hbuf);
  // fused MLP gate/up: out = (h2@wfc + bfc) * silu(h2@wfc2 + bfc2)
  gemm_mlp<<<dim3(48, 16), blk512, 0, stream>>>(
      hbuf, 2048, wfcT, wfc2T, bfc, bfc2, qkvb, 6144, 2048);
  // proj + residual -> d_out
  gemm_n128<1, false><<<dim3(16, 16), blk512, 0, stream>>>(
      qkvb, 6144, wpjT, nullptr, bpj, nullptr, outf, d_out, 2048, 6144);
}

// Round 4
// 690.166 us; speedup vs baseline: 1.1595x; 1.0381x over previous
//
#include <hip/hip_runtime.h>
#include <hip/hip_bf16.h>
#include <math.h>

#define DI __device__ __forceinline__

typedef __bf16 bf16x8 __attribute__((ext_vector_type(8)));
typedef float f32x4 __attribute__((ext_vector_type(4)));
typedef short s16x8 __attribute__((ext_vector_type(8)));

// ---------- helpers ----------
DI unsigned short f2bf(float f) {
  unsigned int u = __builtin_bit_cast(unsigned int, f);
  unsigned int r = (u + 0x7fffu + ((u >> 16) & 1u)) >> 16;
  return (unsigned short)r;
}
DI float bf2f(unsigned short h) {
  unsigned int u = ((unsigned int)h) << 16;
  return __builtin_bit_cast(float, u);
}

DI void gload16(const void* g, void* l) {
  __builtin_amdgcn_global_load_lds(
      (const __attribute__((address_space(1))) void*)g,
      (__attribute__((address_space(3))) void*)l, 16, 0, 0);
}

DI unsigned ldsoff(const void* p) {
  return (unsigned)(size_t)(const __attribute__((address_space(3))) void*)p;
}

// asm ds_read_b128 with compile-time offset: compiler cannot sink/elide it, so
// prefetched fragments stay issued where we put them.
template <int OFF>
DI bf16x8 ds128(unsigned base) {
  bf16x8 r;
  asm volatile("ds_read_b128 %0, %1 offset:%2" : "=v"(r) : "v"(base), "i"(OFF));
  return r;
}
// counted waits + sched_barrier(0) (MFMA intrinsics can hoist past bare
// inline-asm waitcnt; the sched_barrier pins them below).
template <int N>
DI void lgkm() {
  asm volatile("s_waitcnt lgkmcnt(%0)" ::"i"(N));
  __builtin_amdgcn_sched_barrier(0);
}
template <int N>
DI void vmc() {
  asm volatile("s_waitcnt vmcnt(%0)" ::"i"(N));
  __builtin_amdgcn_sched_barrier(0);
}

// 2-D XCD rasterization for GEMMs: XCD grid 2(m) x 4(n); within an XCD,
// m-fastest so the ~32 co-resident blocks form an 8m x 4n rectangle.
DI void xcd_map(int BN, int& m0, int& n0) {
  const int nx = gridDim.x;
  int orig = blockIdx.y * nx + blockIdx.x;
  int xcd = orig & 7, k = orig >> 3;
  int xm = xcd >> 2, xn = xcd & 3;
  int nband = nx >> 2;
  m0 = (xm * 8 + (k & 7)) * 256;
  n0 = (xn * nband + (k >> 3)) * BN;
}

// ---------- transpose + fp32->bf16 cast: out[c][r] = bf16(in[r][c]) ----------
__global__ __launch_bounds__(256)
void transpose_cast_f32(const float* __restrict__ in, unsigned short* __restrict__ out,
                        int R, int C) {
  __shared__ unsigned int t[64 * 65];
  const int r0 = blockIdx.y * 64, c0 = blockIdx.x * 64;
  const int tid = threadIdx.x;
#pragma unroll
  for (int p = 0; p < 4; ++p) {
    int e = p * 1024 + tid * 4;
    int r = e >> 6, c = e & 63;
    float4 v = *(const float4*)(in + (size_t)(r0 + r) * C + c0 + c);
    t[r * 65 + c + 0] = f2bf(v.x);
    t[r * 65 + c + 1] = f2bf(v.y);
    t[r * 65 + c + 2] = f2bf(v.z);
    t[r * 65 + c + 3] = f2bf(v.w);
  }
  __syncthreads();
  const int oc = tid >> 2, ch = tid & 3;
  alignas(16) unsigned short vals[16];
#pragma unroll
  for (int j = 0; j < 16; ++j) vals[j] = (unsigned short)t[(ch * 16 + j) * 65 + oc];
  size_t ob = (size_t)(c0 + oc) * R + r0 + ch * 16;
  *(s16x8*)(out + ob) = *(const s16x8*)(vals);
  *(s16x8*)(out + ob + 8) = *(const s16x8*)(vals + 8);
}

// ---------- V transpose: qkv[b][s][4096+h*128+d] -> vT[bh][d][s] (bf16) ----------
__global__ __launch_bounds__(256)
void transpose_v(const unsigned short* __restrict__ qkv, unsigned short* __restrict__ vT) {
  __shared__ unsigned int t[64 * 65];
  const int s0 = blockIdx.x * 64, d0 = blockIdx.y * 64, bh = blockIdx.z;
  const int b = bh >> 4, h = bh & 15;
  const int tid = threadIdx.x;
#pragma unroll
  for (int p = 0; p < 2; ++p) {
    int id = p * 256 + tid;
    int r = id >> 3, c = (id & 7) * 8;
    s16x8 v = *(const s16x8*)(qkv + (size_t)(b * 2048 + s0 + r) * 6144 + 4096 + h * 128 + d0 + c);
#pragma unroll
    for (int j = 0; j < 8; ++j) t[r * 65 + c + j] = (unsigned short)((const unsigned short*)&v)[j];
  }
  __syncthreads();
  const int oc = tid >> 2, ch = tid & 3;
  alignas(16) unsigned short vals[16];
#pragma unroll
  for (int j = 0; j < 16; ++j) vals[j] = (unsigned short)t[(ch * 16 + j) * 65 + oc];
  size_t ob = (size_t)(bh * 128 + d0 + oc) * 2048 + s0 + ch * 16;
  *(s16x8*)(vT + ob) = *(const s16x8*)(vals);
  *(s16x8*)(vT + ob + 8) = *(const s16x8*)(vals + 8);
}

// ---------- LayerNorm fp32 -> bf16, row = 2048 ----------
__global__ __launch_bounds__(256)
void ln_kernel(const float* __restrict__ x, const float* __restrict__ g,
               const float* __restrict__ bi, unsigned short* __restrict__ y) {
  __shared__ float red[8];
  const int row = blockIdx.x, tid = threadIdx.x;
  const float* xp = x + (size_t)row * 2048 + tid * 8;
  float4 v0 = *(const float4*)xp;
  float4 v1 = *(const float4*)(xp + 4);
  float v[8] = {v0.x, v0.y, v0.z, v0.w, v1.x, v1.y, v1.z, v1.w};
  float s = 0.f;
#pragma unroll
  for (int j = 0; j < 8; ++j) s += v[j];
#pragma unroll
  for (int d = 1; d < 64; d <<= 1) s += __shfl_xor(s, d);
  if ((tid & 63) == 0) red[tid >> 6] = s;
  __syncthreads();
  float mean = (red[0] + red[1] + red[2] + red[3]) * (1.f / 2048.f);
  float dd[8], sq = 0.f;
#pragma unroll
  for (int j = 0; j < 8; ++j) { dd[j] = v[j] - mean; sq += dd[j] * dd[j]; }
#pragma unroll
  for (int d = 1; d < 64; d <<= 1) sq += __shfl_xor(sq, d);
  if ((tid & 63) == 0) red[4 + (tid >> 6)] = sq;
  __syncthreads();
  float var = (red[4] + red[5] + red[6] + red[7]) * (1.f / 2048.f);
  float rs = rsqrtf(var + 1e-5f);
  float4 g0 = *(const float4*)(g + tid * 8), g1 = *(const float4*)(g + tid * 8 + 4);
  float4 b0 = *(const float4*)(bi + tid * 8), b1 = *(const float4*)(bi + tid * 8 + 4);
  float gg[8] = {g0.x, g0.y, g0.z, g0.w, g1.x, g1.y, g1.z, g1.w};
  float bb[8] = {b0.x, b0.y, b0.z, b0.w, b1.x, b1.y, b1.z, b1.w};
  alignas(16) unsigned short o[8];
#pragma unroll
  for (int j = 0; j < 8; ++j) o[j] = f2bf(dd[j] * rs * gg[j] + bb[j]);
  *(s16x8*)(y + (size_t)row * 2048 + tid * 8) = *(const s16x8*)o;
}

// ---------- shared GEMM staging helpers ----------
DI void stage_half(const unsigned short* __restrict__ G, int ld, int rbase, int kt,
                   int h, unsigned short* dst, int tid) {
#pragma unroll
  for (int i = 0; i < 2; ++i) {
    int id = i * 512 + tid;
    int rl = id >> 3, sl = id & 7;
    int ss = sl ^ (rl & 7);
    gload16(G + (size_t)(rbase + h * 128 + rl) * ld + kt + ss * 8,
            (char*)dst + h * 16384 + id * 16);
  }
}

// ---------- 256x256 GEMM (QKV): counted-asm pipelined, 4 clusters/K-tile ----
// Reads pinned via asm ds_read_b128 with counted lgkm so b23 drains under Q1
// and a1 under Q2. Stage placement and vmcnt(6) ledger identical to the
// verified r0 schedule: per K-step stages c1:Ah1(t+1)(2) c3:Bh0(t+2)(2)
// c4:Bh1+Ah0(t+2)(4); vmc<6> at c4 drains exactly all t+1 stages.
// MODE 0: out bf16 = acc + bias ; MODE 1: out f32 = acc + bias + res
template <int MODE>
__global__ __launch_bounds__(512, 2)
void gemm256(const unsigned short* __restrict__ A, int lda,
             const unsigned short* __restrict__ B,
             const float* __restrict__ bias,
             const void* __restrict__ resg,
             void* __restrict__ out, int ldc, int K) {
  __shared__ alignas(16) unsigned short As[2][256 * 64];
  __shared__ alignas(16) unsigned short Bs[2][256 * 64];

  const int tid = threadIdx.x;
  const int l = tid & 63, w = tid >> 6;
  const int wr = w >> 2, wc = w & 3;
  const int lr = l & 15, lg = l >> 4;

  int m0, n0;
  xcd_map(256, m0, n0);

  const int NT = K >> 6;

  f32x4 acc[8][4];
  const f32x4 z4 = {0.f, 0.f, 0.f, 0.f};
#pragma unroll
  for (int i = 0; i < 8; ++i)
#pragma unroll
    for (int j = 0; j < 4; ++j) acc[i][j] = z4;

  // per-lane LDS read bases: row*128 + ((ks ^ (lr&7))<<4), ks = kk*4+lg
  const int s7 = lr & 7;
  const unsigned swz0 = (unsigned)((lg ^ s7) << 4);
  const unsigned swz1 = (unsigned)(((4 | lg) ^ s7) << 4);
  const unsigned rA = (unsigned)((wr * 128 + lr) * 128);
  const unsigned rB = (unsigned)((wc * 64 + lr) * 128);
  const unsigned aA0 = ldsoff(&As[0][0]) + rA + swz0;
  const unsigned aA1 = ldsoff(&As[0][0]) + rA + swz1;
  const unsigned bA0 = ldsoff(&Bs[0][0]) + rB + swz0;
  const unsigned bA1 = ldsoff(&Bs[0][0]) + rB + swz1;

  stage_half(A, lda, m0, 0, 0, As[0], tid);
  stage_half(A, lda, m0, 0, 1, As[0], tid);
  stage_half(B, K, n0, 0, 0, Bs[0], tid);
  stage_half(B, K, n0, 0, 1, Bs[0], tid);
  if (NT > 1) {
    stage_half(B, K, n0, 64, 0, Bs[1], tid);
    stage_half(B, K, n0, 64, 1, Bs[1], tid);
    stage_half(A, lda, m0, 64, 0, As[1], tid);
    asm volatile("s_waitcnt vmcnt(6)" ::: "memory");
  } else {
    asm volatile("s_waitcnt vmcnt(0)" ::: "memory");
  }
  __builtin_amdgcn_s_barrier();

  for (int t = 0; t < NT; ++t) {
    const unsigned co = (unsigned)((t & 1) * 32768);
    const unsigned a0b = aA0 + co, a1b = aA1 + co;
    const unsigned b0b = bA0 + co, b1b = bA1 + co;
    bf16x8 a0[4][2], a1[4][2], bfr[4][2];

    // ---- c1: issue a0(8)+b01(4); stage Ah1(t+1); issue b23(4); lgkm<4>;
    //      Q1 = a0 x b01 (b23 drains underneath) ----
#pragma unroll
    for (int i = 0; i < 4; ++i) {
      a0[i][0] = ds128<0 * 2048>(a0b + i * 2048);
      a0[i][1] = ds128<0 * 2048>(a1b + i * 2048);
    }
#pragma unroll
    for (int j = 0; j < 2; ++j) {
      bfr[j][0] = ds128<0>(b0b + j * 2048);
      bfr[j][1] = ds128<0>(b1b + j * 2048);
    }
    if (t + 1 < NT) stage_half(A, lda, m0, (t + 1) * 64, 1, As[(t & 1) ^ 1], tid);
#pragma unroll
    for (int j = 2; j < 4; ++j) {
      bfr[j][0] = ds128<0>(b0b + j * 2048);
      bfr[j][1] = ds128<0>(b1b + j * 2048);
    }
    lgkm<4>();
    __builtin_amdgcn_s_setprio(1);
#pragma unroll
    for (int i = 0; i < 4; ++i)
#pragma unroll
      for (int j = 0; j < 2; ++j)
#pragma unroll
        for (int kk = 0; kk < 2; ++kk)
          acc[i][j] = __builtin_amdgcn_mfma_f32_16x16x32_bf16(a0[i][kk], bfr[j][kk], acc[i][j], 0, 0, 0);
    __builtin_amdgcn_s_setprio(0);
    __builtin_amdgcn_s_barrier();

    // ---- c2: issue a1(8); lgkm<8> (drains b23); Q2 = a0 x b23 ----
#pragma unroll
    for (int i = 0; i < 4; ++i) {
      a1[i][0] = ds128<8192>(a0b + i * 2048);
      a1[i][1] = ds128<8192>(a1b + i * 2048);
    }
    lgkm<8>();
    __builtin_amdgcn_s_setprio(1);
#pragma unroll
    for (int i = 0; i < 4; ++i)
#pragma unroll
      for (int j = 2; j < 4; ++j)
#pragma unroll
        for (int kk = 0; kk < 2; ++kk)
          acc[i][j] = __builtin_amdgcn_mfma_f32_16x16x32_bf16(a0[i][kk], bfr[j][kk], acc[i][j], 0, 0, 0);
    __builtin_amdgcn_s_setprio(0);
    __builtin_amdgcn_s_barrier();

    // ---- c3: stage Bh0(t+2); lgkm<0> (drains a1); Q3 = a1 x b01 ----
    if (t + 2 < NT) stage_half(B, K, n0, (t + 2) * 64, 0, Bs[t & 1], tid);
    lgkm<0>();
    __builtin_amdgcn_s_setprio(1);
#pragma unroll
    for (int i = 0; i < 4; ++i)
#pragma unroll
      for (int j = 0; j < 2; ++j)
#pragma unroll
        for (int kk = 0; kk < 2; ++kk)
          acc[i + 4][j] = __builtin_amdgcn_mfma_f32_16x16x32_bf16(a1[i][kk], bfr[j][kk], acc[i + 4][j], 0, 0, 0);
    __builtin_amdgcn_s_setprio(0);
    __builtin_amdgcn_s_barrier();

    // ---- c4: stage Bh1(t+2)+Ah0(t+2); Q4 = a1 x b23; vmc ----
    if (t + 2 < NT) {
      stage_half(B, K, n0, (t + 2) * 64, 1, Bs[t & 1], tid);
      stage_half(A, lda, m0, (t + 2) * 64, 0, As[t & 1], tid);
    }
    __builtin_amdgcn_s_setprio(1);
#pragma unroll
    for (int i = 0; i < 4; ++i)
#pragma unroll
      for (int j = 2; j < 4; ++j)
#pragma unroll
        for (int kk = 0; kk < 2; ++kk)
          acc[i + 4][j] = __builtin_amdgcn_mfma_f32_16x16x32_bf16(a1[i][kk], bfr[j][kk], acc[i + 4][j], 0, 0, 0);
    __builtin_amdgcn_s_setprio(0);
    if (t + 2 < NT) { vmc<6>(); } else { vmc<0>(); }
    __builtin_amdgcn_s_barrier();
  }

#pragma unroll
  for (int i = 0; i < 8; ++i) {
    int r0 = m0 + wr * 128 + i * 16 + lg * 4;
#pragma unroll
    for (int j = 0; j < 4; ++j) {
      int col = n0 + wc * 64 + j * 16 + lr;
      float bb = bias[col];
#pragma unroll
      for (int q = 0; q < 4; ++q) {
        size_t off = (size_t)(r0 + q) * ldc + col;
        float v = acc[i][j][q] + bb;
        if (MODE == 0) {
          ((unsigned short*)out)[off] = f2bf(v);
        } else {
          ((float*)out)[off] = v + ((const float*)resg)[off];
        }
      }
    }
  }
}

// ---------- 256x128 GEMM single-B (O-proj / proj): counted-asm 2-cluster ----
// c1: a0+b0 pinned-issued, a1 issued behind them; lgkm<8> lets Q1 start while
// a1 drains under the MFMAs. c2 keeps the verified stage/vmcnt(4) ledger.
// MODE 1: out f32 = acc0 + bias0 + res
template <int MODE, bool DUAL>
__global__ __launch_bounds__(512, 2)
void gemm_n128(const unsigned short* __restrict__ A, int lda,
               const unsigned short* __restrict__ B0,
               const unsigned short* __restrict__ B1,
               const float* __restrict__ bias0, const float* __restrict__ bias1,
               const void* __restrict__ resg,
               void* __restrict__ out, int ldc, int K) {
  __shared__ alignas(16) unsigned short As[2][256 * 64];
  __shared__ alignas(16) unsigned short Bs0[2][128 * 64];

  const int tid = threadIdx.x;
  const int l = tid & 63, w = tid >> 6;
  const int wr = w >> 2, wc = w & 3;
  const int lr = l & 15, lg = l >> 4;

  int m0, n0;
  xcd_map(128, m0, n0);

  const int NT = K >> 6;

  f32x4 acc0[8][2];
  const f32x4 z4 = {0.f, 0.f, 0.f, 0.f};
#pragma unroll
  for (int i = 0; i < 8; ++i)
#pragma unroll
    for (int j = 0; j < 2; ++j) acc0[i][j] = z4;

  const int s7 = lr & 7;
  const unsigned swz0 = (unsigned)((lg ^ s7) << 4);
  const unsigned swz1 = (unsigned)(((4 | lg) ^ s7) << 4);
  const unsigned rA = (unsigned)((wr * 128 + lr) * 128);
  const unsigned rB = (unsigned)((wc * 32 + lr) * 128);
  const unsigned aA0 = ldsoff(&As[0][0]) + rA + swz0;
  const unsigned aA1 = ldsoff(&As[0][0]) + rA + swz1;
  const unsigned bA0 = ldsoff(&Bs0[0][0]) + rB + swz0;
  const unsigned bA1 = ldsoff(&Bs0[0][0]) + rB + swz1;

  // prologue
  stage_half(A, lda, m0, 0, 0, As[0], tid);
  stage_half(A, lda, m0, 0, 1, As[0], tid);
  stage_half(B0, K, n0, 0, 0, Bs0[0], tid);
  if (NT > 1) {
    stage_half(B0, K, n0, 64, 0, Bs0[1], tid);
    stage_half(A, lda, m0, 64, 0, As[1], tid);
    asm volatile("s_waitcnt vmcnt(4)" ::: "memory");
  } else {
    asm volatile("s_waitcnt vmcnt(0)" ::: "memory");
  }
  __builtin_amdgcn_s_barrier();

  for (int t = 0; t < NT; ++t) {
    const int cur = t & 1;
    const unsigned ca = aA0 + (unsigned)(cur * 32768);
    const unsigned ca1 = aA1 + (unsigned)(cur * 32768);
    const unsigned cb = bA0 + (unsigned)(cur * 16384);
    const unsigned cb1 = bA1 + (unsigned)(cur * 16384);
    bf16x8 a0[4][2], a1[4][2], b0f[2][2];

    // ---- c1: issue a0(8)+b0(4); stage Ah1(t+1); issue a1(8); lgkm<8>;
    //      Q1 = a0 x b0 (a1 drains underneath) ----
#pragma unroll
    for (int i = 0; i < 4; ++i) {
      a0[i][0] = ds128<0>(ca + i * 2048);
      a0[i][1] = ds128<0>(ca1 + i * 2048);
    }
#pragma unroll
    for (int j = 0; j < 2; ++j) {
      b0f[j][0] = ds128<0>(cb + j * 2048);
      b0f[j][1] = ds128<0>(cb1 + j * 2048);
    }
    if (t + 1 < NT) stage_half(A, lda, m0, (t + 1) * 64, 1, As[cur ^ 1], tid);
#pragma unroll
    for (int i = 0; i < 4; ++i) {
      a1[i][0] = ds128<8192>(ca + i * 2048);
      a1[i][1] = ds128<8192>(ca1 + i * 2048);
    }
    lgkm<8>();
    __builtin_amdgcn_s_setprio(1);
#pragma unroll
    for (int i = 0; i < 4; ++i)
#pragma unroll
      for (int j = 0; j < 2; ++j)
#pragma unroll
        for (int kk = 0; kk < 2; ++kk)
          acc0[i][j] = __builtin_amdgcn_mfma_f32_16x16x32_bf16(a0[i][kk], b0f[j][kk], acc0[i][j], 0, 0, 0);
    __builtin_amdgcn_s_setprio(0);
    __builtin_amdgcn_s_barrier();

    // ---- c2: stage B0(t+2); lgkm<0> (drain a1); stage Ah0(t+2); Q2 ----
    if (t + 2 < NT) stage_half(B0, K, n0, (t + 2) * 64, 0, Bs0[cur], tid);
    lgkm<0>();
    if (t + 2 < NT) stage_half(A, lda, m0, (t + 2) * 64, 0, As[cur], tid);
    __builtin_amdgcn_s_setprio(1);
#pragma unroll
    for (int i = 0; i < 4; ++i)
#pragma unroll
      for (int j = 0; j < 2; ++j)
#pragma unroll
        for (int kk = 0; kk < 2; ++kk)
          acc0[i + 4][j] = __builtin_amdgcn_mfma_f32_16x16x32_bf16(a1[i][kk], b0f[j][kk], acc0[i + 4][j], 0, 0, 0);
    __builtin_amdgcn_s_setprio(0);
    if (t + 2 < NT) { vmc<4>(); } else { vmc<0>(); }
    __builtin_amdgcn_s_barrier();
  }

  // epilogue
#pragma unroll
  for (int i = 0; i < 8; ++i) {
    int r0 = m0 + wr * 128 + i * 16 + lg * 4;
#pragma unroll
    for (int j = 0; j < 2; ++j) {
      int col = n0 + wc * 32 + j * 16 + lr;
      float bb0 = bias0[col];
#pragma unroll
      for (int q = 0; q < 4; ++q) {
        size_t off = (size_t)(r0 + q) * ldc + col;
        float v = acc0[i][j][q] + bb0;
        ((float*)out)[off] = v + ((const float*)resg)[off];
      }
    }
  }
}

// ---------- MLP dual GEMM: 256x128, counted-wait asm-pipelined 4-phase -------
DI void mmq(f32x4 (&acc)[8][2], int io, const bf16x8 (&af)[4][2], const bf16x8 (&bf)[2][2]) {
#pragma unroll
  for (int kk = 0; kk < 2; ++kk)
#pragma unroll
    for (int i = 0; i < 4; ++i)
#pragma unroll
      for (int j = 0; j < 2; ++j)
        acc[io + i][j] = __builtin_amdgcn_mfma_f32_16x16x32_bf16(af[i][kk], bf[j][kk], acc[io + i][j], 0, 0, 0);
}

#define RDA(dst, B0_, B1_, OFS)                                        \
  dst[0][0] = ds128<(OFS) + 0>(B0_);    dst[0][1] = ds128<(OFS) + 0>(B1_);    \
  dst[1][0] = ds128<(OFS) + 2048>(B0_); dst[1][1] = ds128<(OFS) + 2048>(B1_); \
  dst[2][0] = ds128<(OFS) + 4096>(B0_); dst[2][1] = ds128<(OFS) + 4096>(B1_); \
  dst[3][0] = ds128<(OFS) + 6144>(B0_); dst[3][1] = ds128<(OFS) + 6144>(B1_);

#define RDB(dst, B0_, B1_, OFS)                                        \
  dst[0][0] = ds128<(OFS) + 0>(B0_);    dst[0][1] = ds128<(OFS) + 0>(B1_);    \
  dst[1][0] = ds128<(OFS) + 2048>(B0_); dst[1][1] = ds128<(OFS) + 2048>(B1_);

#define MLP_ITER(t, CUR, A0C, B0C, B1C, A1C, A0N, B0N)                         \
  {                                                                            \
    /* P1: issue b1(t); wait a0(t),b0(t); Q1 = a0 x b0 -> acc0 lo */           \
    RDB(B1C, cA0, cA1, (CUR) * 16384);                                         \
    lgkm<4>();                                                                 \
    __builtin_amdgcn_s_setprio(1);                                             \
    mmq(acc0, 0, A0C, B0C);                                                    \
    __builtin_amdgcn_s_setprio(0);                                             \
    __builtin_amdgcn_sched_barrier(0);                                         \
    __builtin_amdgcn_s_barrier();                                              \
    /* P2: stage B0(t+2); issue a1(t); wait b1(t); Q2 = a0 x b1 -> acc1 lo */  \
    if ((t) + 2 < NT) stage_half(B0, K, n0, ((t) + 2) * 64, 0, Bs0[CUR], tid); \
    RDA(A1C, aA0, aA1, (CUR) * 32768 + 8192);                                  \
    lgkm<8>();                                                                 \
    __builtin_amdgcn_s_setprio(1);                                             \
    mmq(acc1, 0, A0C, B1C);                                                    \
    __builtin_amdgcn_s_setprio(0);                                             \
    if ((t) + 2 < NT) { vmc<2>(); } else { vmc<0>(); }                         \
    __builtin_amdgcn_s_barrier();                                              \
    /* P3: stage B1(t+2); issue a0(t+1); wait a1(t); Q3 = a1 x b0 -> acc0 hi */\
    if ((t) + 2 < NT) stage_half(B1, K, n0, ((t) + 2) * 64, 0, Bs1[CUR], tid); \
    RDA(A0N, aA0, aA1, ((CUR) ^ 1) * 32768);                                   \
    lgkm<8>();                                                                 \
    __builtin_amdgcn_s_setprio(1);                                             \
    mmq(acc0, 4, A1C, B0C);                                                    \
    __builtin_amdgcn_s_setprio(0);                                             \
    __builtin_amdgcn_sched_barrier(0);                                         \
    __builtin_amdgcn_s_barrier();                                              \
    /* P4: stage A(t+2) both halves; issue b0(t+1); Q4 = a1 x b1 -> acc1 hi */ \
    if ((t) + 2 < NT) {                                                        \
      stage_half(A, lda, m0, ((t) + 2) * 64, 0, As[CUR], tid);                 \
      stage_half(A, lda, m0, ((t) + 2) * 64, 1, As[CUR], tid);                 \
    }                                                                          \
    RDB(B0N, bA0, bA1, ((CUR) ^ 1) * 16384);                                   \
    __builtin_amdgcn_sched_barrier(0);                                         \
    __builtin_amdgcn_s_setprio(1);                                             \
    mmq(acc1, 4, A1C, B1C);                                                    \
    __builtin_amdgcn_s_setprio(0);                                             \
    __builtin_amdgcn_sched_barrier(0);                                         \
    __builtin_amdgcn_s_barrier();                                              \
  }

__global__ __launch_bounds__(512, 2)
void gemm_mlp(const unsigned short* __restrict__ A, int lda,
              const unsigned short* __restrict__ B0,
              const unsigned short* __restrict__ B1,
              const float* __restrict__ bias0, const float* __restrict__ bias1,
              unsigned short* __restrict__ out, int ldc, int K) {
  __shared__ alignas(16) unsigned short As[2][256 * 64];
  __shared__ alignas(16) unsigned short Bs0[2][128 * 64];
  __shared__ alignas(16) unsigned short Bs1[2][128 * 64];

  const int tid = threadIdx.x;
  const int l = tid & 63, w = tid >> 6;
  const int wr = w >> 2, wc = w & 3;
  const int lr = l & 15, lg = l >> 4;

  int m0, n0;
  xcd_map(128, m0, n0);
  const int NT = K >> 6;  // even (K=2048 -> 32)

  f32x4 acc0[8][2], acc1[8][2];
  const f32x4 z4 = {0.f, 0.f, 0.f, 0.f};
#pragma unroll
  for (int i = 0; i < 8; ++i)
#pragma unroll
    for (int j = 0; j < 2; ++j) { acc0[i][j] = z4; acc1[i][j] = z4; }

  const int s7 = lr & 7;
  const unsigned swz0 = (unsigned)((lg ^ s7) << 4);
  const unsigned swz1 = (unsigned)(((4 | lg) ^ s7) << 4);
  const unsigned rA = (unsigned)((wr * 128 + lr) * 128);
  const unsigned rB = (unsigned)((wc * 32 + lr) * 128);
  const unsigned aA0 = ldsoff(&As[0][0]) + rA + swz0;
  const unsigned aA1 = ldsoff(&As[0][0]) + rA + swz1;
  const unsigned bA0 = ldsoff(&Bs0[0][0]) + rB + swz0;
  const unsigned bA1 = ldsoff(&Bs0[0][0]) + rB + swz1;
  const unsigned cA0 = ldsoff(&Bs1[0][0]) + rB + swz0;
  const unsigned cA1 = ldsoff(&Bs1[0][0]) + rB + swz1;

  bf16x8 a0X[4][2], a1X[4][2], b0X[2][2], b1X[2][2];
  bf16x8 a0Y[4][2], a1Y[4][2], b0Y[2][2], b1Y[2][2];

  stage_half(A, lda, m0, 0, 0, As[0], tid);
  stage_half(A, lda, m0, 0, 1, As[0], tid);
  stage_half(B0, K, n0, 0, 0, Bs0[0], tid);
  stage_half(B1, K, n0, 0, 0, Bs1[0], tid);
  stage_half(B0, K, n0, 64, 0, Bs0[1], tid);
  stage_half(B1, K, n0, 64, 0, Bs1[1], tid);
  stage_half(A, lda, m0, 64, 0, As[1], tid);
  stage_half(A, lda, m0, 64, 1, As[1], tid);
  vmc<8>();
  __builtin_amdgcn_s_barrier();
  RDA(a0X, aA0, aA1, 0);
  RDB(b0X, bA0, bA1, 0);

  for (int t = 0; t < NT; t += 2) {
    MLP_ITER(t, 0, a0X, b0X, b1X, a1X, a0Y, b0Y);
    MLP_ITER(t + 1, 1, a0Y, b0Y, b1Y, a1Y, a0X, b0X);
  }

  // epilogue: out bf16 = (acc0+bias0) * silu(acc1+bias1)
#pragma unroll
  for (int i = 0; i < 8; ++i) {
    int r0 = m0 + wr * 128 + i * 16 + lg * 4;
#pragma unroll
    for (int j = 0; j < 2; ++j) {
      int col = n0 + wc * 32 + j * 16 + lr;
      float bb0 = bias0[col];
      float bb1 = bias1[col];
#pragma unroll
      for (int q = 0; q < 4; ++q) {
        size_t off = (size_t)(r0 + q) * ldc + col;
        float v = acc0[i][j][q] + bb0;
        float gt = acc1[i][j][q] + bb1;
        out[off] = f2bf(v * (gt / (1.f + expf(-gt))));
      }
    }
  }
}

// ---------- flash attention: paired q-tiles, XCD-local bh, coalesced out ----
__global__ __launch_bounds__(256, 2)
void attn_kernel(const unsigned short* __restrict__ qkv,
                 const unsigned short* __restrict__ vT,
                 unsigned short* __restrict__ ctx) {
  __shared__ unsigned short Ks[64 * 128];
  __shared__ unsigned short Vs[128 * 64];
  __shared__ unsigned short Ps[4][16 * 80];
  __shared__ unsigned short Ob[4][16 * 136];

  const int g = blockIdx.x;
  const int xcd = g & 7, slot = g >> 3;
  const int bh = xcd * 4 + (slot & 3);
  const int pid = slot >> 2;
  const int b = bh >> 4, h = bh & 15;
  const int tid = threadIdx.x, l = tid & 63, w = tid >> 6;
  const int lr = l & 15, lg = l >> 4;
  const float slope2 = exp2f(-0.5f * (float)(h + 1)) * 1.44269504f;
  const float SC2 = 0.0078125f * 1.44269504f;

  const int krow = tid >> 4, kcb = tid & 15;
  const int vrow = tid >> 3, vcb = tid & 7;
  const unsigned short* kbase = qkv + (size_t)(b * 2048 + krow) * 6144 + 2048 + h * 128 + kcb * 8;
  const unsigned short* vbase = vT + (size_t)(bh * 128 + vrow) * 2048 + vcb * 8;
  char* kdst = (char*)Ks + krow * 256 + ((kcb ^ (krow & 7)) << 4);
  char* vdst = (char*)Vs + vrow * 128 + ((vcb ^ (vrow & 7)) << 4);

  int4 kr[4], vr[4];
#pragma unroll
  for (int p = 0; p < 4; ++p) {
    kr[p] = *(const int4*)(kbase + (size_t)p * 16 * 6144);
    vr[p] = *(const int4*)(vbase + (size_t)p * 32 * 2048);
  }

  for (int tq = 0; tq < 2; ++tq) {
    const int qb = tq ? (31 - pid) : pid;
    const int q0 = qb * 64;
    bf16x8 aq[4];
    {
      const unsigned short* qp =
          qkv + (size_t)(b * 2048 + q0 + w * 16 + lr) * 6144 + h * 128 + lg * 8;
#pragma unroll
      for (int kk = 0; kk < 4; ++kk) aq[kk] = *(const bf16x8*)(qp + kk * 32);
    }
    const f32x4 z4 = {0.f, 0.f, 0.f, 0.f};
    f32x4 acc[8];
#pragma unroll
    for (int dt = 0; dt < 8; ++dt) acc[dt] = z4;
    float m_r[4] = {-INFINITY, -INFINITY, -INFINITY, -INFINITY};
    float l_r[4] = {0.f, 0.f, 0.f, 0.f};
    const int ibase = q0 + w * 16 + lg * 4;
    const int nc = qb + 1;

    for (int c = 0; c < nc; ++c) {
      const int kv0 = c * 64;
      __syncthreads();
#pragma unroll
      for (int p = 0; p < 4; ++p) {
        *(int4*)(kdst + p * 4096) = kr[p];
        *(int4*)(vdst + p * 4096) = vr[p];
      }
      __syncthreads();
      {
        int nxt = (c + 1 < nc) ? (c + 1) * 64 : (tq == 0 ? 0 : -1);
        if (nxt >= 0) {
#pragma unroll
          for (int p = 0; p < 4; ++p) {
            kr[p] = *(const int4*)(kbase + (size_t)nxt * 6144 + (size_t)p * 16 * 6144);
            vr[p] = *(const int4*)(vbase + nxt + (size_t)p * 32 * 2048);
          }
        }
      }

      f32x4 sc[4];
#pragma unroll
      for (int t = 0; t < 4; ++t) sc[t] = z4;
      __builtin_amdgcn_s_setprio(1);
#pragma unroll
      for (int t = 0; t < 4; ++t) {
#pragma unroll
        for (int kk = 0; kk < 4; ++kk) {
          int row = t * 16 + lr;
          int bo = (row * 256 + kk * 64 + lg * 16) ^ ((row & 7) << 4);
          bf16x8 bk = *(const bf16x8*)((const char*)Ks + bo);
          sc[t] = __builtin_amdgcn_mfma_f32_16x16x32_bf16(aq[kk], bk, sc[t], 0, 0, 0);
        }
      }
      __builtin_amdgcn_s_setprio(0);
      float cmax[4] = {-INFINITY, -INFINITY, -INFINITY, -INFINITY};
#pragma unroll
      for (int t = 0; t < 4; ++t)
#pragma unroll
        for (int q = 0; q < 4; ++q) {
          int j = kv0 + t * 16 + lr;
          int i = ibase + q;
          float s = sc[t][q] * SC2 + slope2 * (float)(j - i);
          if (j > i) s = -1e9f;
          sc[t][q] = s;
          cmax[q] = fmaxf(cmax[q], s);
        }
#pragma unroll
      for (int q = 0; q < 4; ++q) {
        float v = cmax[q];
        v = fmaxf(v, __shfl_xor(v, 1));
        v = fmaxf(v, __shfl_xor(v, 2));
        v = fmaxf(v, __shfl_xor(v, 4));
        v = fmaxf(v, __shfl_xor(v, 8));
        cmax[q] = v;
      }
      float alpha[4], rsum[4];
#pragma unroll
      for (int q = 0; q < 4; ++q) {
        float mn = fmaxf(m_r[q], cmax[q]);
        alpha[q] = exp2f(m_r[q] - mn);
        m_r[q] = mn;
        rsum[q] = 0.f;
      }
#pragma unroll
      for (int t = 0; t < 4; ++t)
#pragma unroll
        for (int q = 0; q < 4; ++q) {
          float p = exp2f(sc[t][q] - m_r[q]);
          rsum[q] += p;
          sc[t][q] = p;
        }
#pragma unroll
      for (int q = 0; q < 4; ++q) {
        float v = rsum[q];
        v += __shfl_xor(v, 1);
        v += __shfl_xor(v, 2);
        v += __shfl_xor(v, 4);
        v += __shfl_xor(v, 8);
        l_r[q] = l_r[q] * alpha[q] + v;
      }
#pragma unroll
      for (int dt = 0; dt < 8; ++dt)
#pragma unroll
        for (int q = 0; q < 4; ++q) acc[dt][q] *= alpha[q];
#pragma unroll
      for (int t = 0; t < 4; ++t)
#pragma unroll
        for (int q = 0; q < 4; ++q)
          Ps[w][(lg * 4 + q) * 80 + t * 16 + lr] = f2bf(sc[t][q]);
      __builtin_amdgcn_s_setprio(1);
#pragma unroll
      for (int kc = 0; kc < 2; ++kc) {
        bf16x8 ap = *(const bf16x8*)(&Ps[w][lr * 80 + kc * 32 + lg * 8]);
#pragma unroll
        for (int dt = 0; dt < 8; ++dt) {
          int row = dt * 16 + lr;
          int bo = (row * 128 + kc * 64 + lg * 16) ^ ((row & 7) << 4);
          bf16x8 bv = *(const bf16x8*)((const char*)Vs + bo);
          acc[dt] = __builtin_amdgcn_mfma_f32_16x16x32_bf16(ap, bv, acc[dt], 0, 0, 0);
        }
      }
      __builtin_amdgcn_s_setprio(0);
    }

    // ---- coalesced epilogue: wave-private LDS transpose, 64B-sector stores --
    unsigned short* Kw = &Ob[w][0];
#pragma unroll
    for (int q = 0; q < 4; ++q) {
      float inv = 1.f / l_r[q];
      int rl = lg * 4 + q;
#pragma unroll
      for (int dt = 0; dt < 8; ++dt)
        Kw[rl * 136 + dt * 16 + lr] = f2bf(acc[dt][q] * inv);
    }
    const int rr = l >> 2, c4 = l & 3;
    const unsigned short* srow = Kw + rr * 136 + c4 * 8;
    size_t gb = (size_t)(b * 2048 + q0 + w * 16 + rr) * 2048 + h * 128 + c4 * 8;
#pragma unroll
    for (int k = 0; k < 4; ++k)
      *(s16x8*)(ctx + gb + k * 32) = *(const s16x8*)(srow + k * 32);
  }
}

// ---------- launch ----------
extern "C" void kernel_launch(void* const* d_in, const int* in_sizes, int n_in,
                              void* d_out, int out_size, void* d_ws, size_t ws_size,
                              hipStream_t stream) {
  const float* hs   = (const float*)d_in[0];
  const float* ln1g = (const float*)d_in[3];
  const float* ln1b = (const float*)d_in[4];
  const float* wqkv = (const float*)d_in[5];
  const float* bqkv = (const float*)d_in[6];
  const float* wo   = (const float*)d_in[7];
  const float* bo   = (const float*)d_in[8];
  const float* ln2g = (const float*)d_in[9];
  const float* ln2b = (const float*)d_in[10];
  const float* wfc  = (const float*)d_in[11];
  const float* bfc  = (const float*)d_in[12];
  const float* wfc2 = (const float*)d_in[13];
  const float* bfc2 = (const float*)d_in[14];
  const float* wpj  = (const float*)d_in[15];
  const float* bpj  = (const float*)d_in[16];

  char* ws = (char*)d_ws;
  unsigned short* woT   = (unsigned short*)(ws + 0);          //  8 MB
  unsigned short* wfcT  = (unsigned short*)(ws + 8388608);    // 24 MB
  unsigned short* wfc2T = (unsigned short*)(ws + 33554432);   // 24 MB
  unsigned short* hbuf  = (unsigned short*)(ws + 58720256);   // 16 MB
  unsigned short* qkvb  = (unsigned short*)(ws + 75497472);   // 48 MB (later mlp_in)
  unsigned short* wqkvT = (unsigned short*)(ws + 125829120);  // 24 MB (later wpjT)
  unsigned short* vTb   = (unsigned short*)(ws + 150994944);  // 16 MB
  unsigned short* ctxb  = (unsigned short*)(ws + 167772160);  // 16 MB
  unsigned short* wpjT  = wqkvT;
  float* outf = (float*)d_out;

  dim3 blk(256), blk512(512);
  transpose_cast_f32<<<dim3(96, 32), blk, 0, stream>>>(wqkv, wqkvT, 2048, 6144);
  transpose_cast_f32<<<dim3(32, 32), blk, 0, stream>>>(wo, woT, 2048, 2048);
  transpose_cast_f32<<<dim3(96, 32), blk, 0, stream>>>(wfc, wfcT, 2048, 6144);
  transpose_cast_f32<<<dim3(96, 32), blk, 0, stream>>>(wfc2, wfc2T, 2048, 6144);
  ln_kernel<<<dim3(4096), blk, 0, stream>>>(hs, ln1g, ln1b, hbuf);
  // QKV: [4096,2048] x [6144,2048]^T -> [4096,6144] bf16
  gemm256<0><<<dim3(24, 16), blk512, 0, stream>>>(hbuf, 2048, wqkvT, bqkv, nullptr,
                                                  qkvb, 6144, 2048);
  transpose_v<<<dim3(32, 2, 32), blk, 0, stream>>>(qkvb, vTb);
  transpose_cast_f32<<<dim3(32, 96), blk, 0, stream>>>(wpj, wpjT, 6144, 2048);
  // attention (paired q-tiles, XCD-local bh mapping)
  attn_kernel<<<dim3(512), blk, 0, stream>>>(qkvb, vTb, ctxb);
  // O-proj + residual -> d_out f32  (grid 256 = full GPU)
  gemm_n128<1, false><<<dim3(16, 16), blk512, 0, stream>>>(
      ctxb, 2048, woT, nullptr, bo, nullptr, hs, d_out, 2048, 2048);
  ln_kernel<<<dim3(4096), blk, 0, stream>>>(outf, ln2g, ln2b, hbuf);
  // fused MLP gate/up: out = (h2@wfc + bfc) * silu(h2@wfc2 + bfc2)
  gemm_mlp<<<dim3(48, 16), blk512, 0, stream>>>(
      hbuf, 2048, wfcT, wfc2T, bfc, bfc2, qkvb, 6144, 2048);
  // proj + residual -> d_out
  gemm_n128<1, false><<<dim3(16, 16), blk512, 0, stream>>>(
      qkvb, 6144, wpjT, nullptr, bpj, nullptr, outf, d_out, 2048, 6144);
}